// Round 4
// baseline (1097.405 us; speedup 1.0000x reference)
//
#include <hip/hip_runtime.h>
#include <hip/hip_bf16.h>
#include <math.h>

typedef __attribute__((ext_vector_type(8))) __bf16 bf16x8;
typedef __attribute__((ext_vector_type(2))) __bf16 bf16x2;
typedef __attribute__((ext_vector_type(4))) float f32x4;

#define LSTR 40   // LDS row stride (elements), pads 32-wide K tiles to kill bank conflicts

// ---------------- GEMM: C[M,N] = A[M,K] @ Bt[N,K]^T, bf16 in, fp32 accum, bf16 out ----------
__global__ __launch_bounds__(256) void gemm_bt(const __bf16* __restrict__ A,
                                               const __bf16* __restrict__ Bt,
                                               __bf16* __restrict__ C,
                                               int M, int N, int K) {
    __shared__ __bf16 As[128 * LSTR];
    __shared__ __bf16 Bs[128 * LSTR];
    const int t = threadIdx.x;
    const int lane = t & 63;
    const int wid = t >> 6;
    const int wm = (wid >> 1) << 6;
    const int wn = (wid & 1) << 6;
    const int bm = blockIdx.x * 128;
    const int bn = blockIdx.y * 128;

    const int lr = t >> 2;        // 0..63
    const int lc = (t & 3) << 3;  // 0,8,16,24

    f32x4 acc[4][4];
#pragma unroll
    for (int i = 0; i < 4; i++)
#pragma unroll
        for (int j = 0; j < 4; j++) acc[i][j] = (f32x4){0.f, 0.f, 0.f, 0.f};

    const int m16 = lane & 15;
    const int k8 = (lane >> 4) << 3;

    for (int k0 = 0; k0 < K; k0 += 32) {
        bf16x8 a0 = *(const bf16x8*)(A + (size_t)(bm + lr) * K + k0 + lc);
        bf16x8 a1 = *(const bf16x8*)(A + (size_t)(bm + lr + 64) * K + k0 + lc);
        bf16x8 b0 = *(const bf16x8*)(Bt + (size_t)(bn + lr) * K + k0 + lc);
        bf16x8 b1 = *(const bf16x8*)(Bt + (size_t)(bn + lr + 64) * K + k0 + lc);
        __syncthreads();
        *(bf16x8*)(As + lr * LSTR + lc) = a0;
        *(bf16x8*)(As + (lr + 64) * LSTR + lc) = a1;
        *(bf16x8*)(Bs + lr * LSTR + lc) = b0;
        *(bf16x8*)(Bs + (lr + 64) * LSTR + lc) = b1;
        __syncthreads();
        bf16x8 af[4], bfr[4];
#pragma unroll
        for (int i = 0; i < 4; i++) {
            af[i] = *(const bf16x8*)(As + (wm + 16 * i + m16) * LSTR + k8);
            bfr[i] = *(const bf16x8*)(Bs + (wn + 16 * i + m16) * LSTR + k8);
        }
#pragma unroll
        for (int i = 0; i < 4; i++)
#pragma unroll
            for (int j = 0; j < 4; j++)
                acc[i][j] = __builtin_amdgcn_mfma_f32_16x16x32_bf16(af[i], bfr[j], acc[i][j], 0, 0, 0);
    }
    const int r4 = (lane >> 4) << 2;
#pragma unroll
    for (int i = 0; i < 4; i++) {
#pragma unroll
        for (int j = 0; j < 4; j++) {
            int col = bn + wn + 16 * j + m16;
#pragma unroll
            for (int r = 0; r < 4; r++) {
                int row = bm + wm + 16 * i + r4 + r;
                C[(size_t)row * N + col] = (__bf16)acc[i][j][r];
            }
        }
    }
}

// ---------------- x (fp32) -> padded bf16 [Mpad,64], zeros outside ----------------
__global__ void pack_x_k(const float* __restrict__ x, __bf16* __restrict__ xp, int rows_real) {
    int i = blockIdx.x * 256 + threadIdx.x;
    int n = i >> 6, c = i & 63;
    float v = 0.f;
    if (n < rows_real && c < 50) v = x[n * 50 + c];
    xp[(size_t)n * 64 + c] = (__bf16)v;
}

// ---------------- transpose+pad: W[K,N] fp32 -> WT[Np,Kp] bf16 (zeros outside) -----------
__global__ void transpose_pad_k(const float* __restrict__ W, __bf16* __restrict__ WT,
                                int K, int N, int Kp, int Np) {
    __shared__ float tile[32][33];
    int bx = blockIdx.x, by = blockIdx.y;
    int tx = threadIdx.x & 31, ty = threadIdx.x >> 5;  // 32 x 8
#pragma unroll
    for (int r = ty; r < 32; r += 8) {
        int k = by * 32 + r, n = bx * 32 + tx;
        float v = 0.f;
        if (k < K && n < N) v = W[(size_t)k * N + n];
        tile[r][tx] = v;
    }
    __syncthreads();
#pragma unroll
    for (int r = ty; r < 32; r += 8) {
        int n = bx * 32 + r, k = by * 32 + tx;
        if (n < Np && k < Kp) WT[(size_t)n * Kp + k] = (__bf16)tile[tx][r];
    }
}

// ---------------- edge_index dtype probe: 1 if int64 (odd int32 slots all zero) -----------
__global__ void probe_ei_k(const int* __restrict__ ei, int* __restrict__ flag) {
    if (blockIdx.x == 0 && threadIdx.x == 0) {
        int all0 = 1;
        for (int i = 0; i < 64; i++)
            if (ei[2 * i + 1] != 0) { all0 = 0; break; }
        *flag = all0;
    }
}

__device__ __forceinline__ int load_ei(const int* ei, int idx, int is64) {
    return is64 ? ei[2 * idx] : ei[idx];
}

// ---------------- CSR build (by dst, self-loops appended) ----------------
__global__ void hist_k(const int* __restrict__ ei, const int* __restrict__ flag,
                       int* __restrict__ cnt, int E, int Nn) {
    int e = blockIdx.x * 256 + threadIdx.x;
    if (e >= E + Nn) return;
    int is64 = *flag;
    int d = (e < E) ? load_ei(ei, E + e, is64) : (e - E);
    d = min(max(d, 0), Nn - 1);
    atomicAdd(&cnt[d], 1);
}

__global__ __launch_bounds__(1024) void scan_k(const int* __restrict__ cnt, int* __restrict__ row_ptr,
                                               int Nn, int total) {
    __shared__ int part[1024];
    int t = threadIdx.x;
    int chunk = (Nn + 1023) >> 10;
    int lo = t * chunk;
    int hi = lo + chunk; if (hi > Nn) hi = Nn; if (lo > Nn) lo = Nn;
    int s = 0;
    for (int i = lo; i < hi; i++) s += cnt[i];
    part[t] = s;
    __syncthreads();
    for (int off = 1; off < 1024; off <<= 1) {
        int v = (t >= off) ? part[t - off] : 0;
        __syncthreads();
        part[t] += v;
        __syncthreads();
    }
    int run = part[t] - s;
    for (int i = lo; i < hi; i++) { row_ptr[i] = run; run += cnt[i]; }
    if (t == 0) row_ptr[Nn] = total;
}

__global__ void fill_csr_k(const int* __restrict__ ei, const int* __restrict__ flag,
                           const int* __restrict__ row_ptr, int* __restrict__ cursor,
                           int* __restrict__ src_csr, int E, int Nn) {
    int e = blockIdx.x * 256 + threadIdx.x;
    if (e >= E + Nn) return;
    int is64 = *flag;
    int d = (e < E) ? load_ei(ei, E + e, is64) : (e - E);
    int s = (e < E) ? load_ei(ei, e, is64) : (e - E);
    d = min(max(d, 0), Nn - 1);
    s = min(max(s, 0), Nn - 1);
    int slot = row_ptr[d] + atomicAdd(&cursor[d], 1);
    src_csr[slot] = s;
}

// ---------------- per-(node,head) attention dots (a vectors fp32) ----------------
// Cpad = per-head column stride in XL
__global__ void alpha_k(const __bf16* __restrict__ XL, int ld, const float* __restrict__ a_src,
                        const float* __restrict__ a_dst, float* __restrict__ asrc,
                        float* __restrict__ adst, int Nn, int H, int C, int Cpad) {
    int gw = (blockIdx.x * 256 + threadIdx.x) >> 6;
    int lane = threadIdx.x & 63;
    if (gw >= Nn * H) return;
    int n = gw / H, h = gw - n * H;
    const __bf16* row = XL + (size_t)n * ld + h * Cpad;
    const float* as = a_src + h * C;
    const float* ad = a_dst + h * C;
    float s = 0.f, d = 0.f;
    for (int c = lane; c < C; c += 64) {
        float v = (float)row[c];
        s += v * as[c];
        d += v * ad[c];
    }
#pragma unroll
    for (int off = 32; off; off >>= 1) {
        s += __shfl_down(s, off);
        d += __shfl_down(d, off);
    }
    if (lane == 0) { asrc[n * H + h] = s; adst[n * H + h] = d; }
}

// ---------------- per-node segment softmax -> edge weights (one wave per node) -----------
__global__ void attn_k(const int* __restrict__ row_ptr, const int* __restrict__ src_csr,
                       const float* __restrict__ asrc, const float* __restrict__ adst,
                       float* __restrict__ w, int Nn, int H) {
    int gw = (blockIdx.x * 256 + threadIdx.x) >> 6;
    int lane = threadIdx.x & 63;
    if (gw >= Nn) return;
    int n = gw;
    int base = row_ptr[n], deg = row_ptr[n + 1] - base;
    for (int h = 0; h < H; h++) {
        float ad = adst[n * H + h];
        float m = -1e30f;
        for (int s = lane; s < deg; s += 64) {
            float e = asrc[src_csr[base + s] * H + h] + ad;
            e = e > 0.f ? e : 0.2f * e;
            m = fmaxf(m, e);
        }
#pragma unroll
        for (int off = 1; off < 64; off <<= 1) m = fmaxf(m, __shfl_xor(m, off));
        float sum = 0.f;
        for (int s = lane; s < deg; s += 64) {
            float e = asrc[src_csr[base + s] * H + h] + ad;
            e = e > 0.f ? e : 0.2f * e;
            sum += __expf(e - m);
        }
#pragma unroll
        for (int off = 1; off < 64; off <<= 1) sum += __shfl_xor(sum, off);
        float inv = 1.f / (sum + 1e-16f);
        for (int s = lane; s < deg; s += 64) {
            float e = asrc[src_csr[base + s] * H + h] + ad;
            e = e > 0.f ? e : 0.2f * e;
            w[(size_t)(base + s) * H + h] = __expf(e - m) * inv;
        }
    }
}

// ------- XCD-sharded aggregation, layers 1/2 (H=4, C=256, ld=1024) ----------
// grid (8, ceil(Nn/4)); blockIdx.x = column chunk (128 cols) -> lin%8 pins chunk->XCD.
// wave = node, lane covers 2 cols via bf16x2. SK += agg + bias + sb, in place.
__global__ __launch_bounds__(256) void agg_skip2(const __bf16* __restrict__ XL,
                                                 const float* __restrict__ w,
                                                 const int* __restrict__ row_ptr,
                                                 const int* __restrict__ src_csr,
                                                 const float* __restrict__ bias,
                                                 const float* __restrict__ sb,
                                                 __bf16* __restrict__ SK, int Nn) {
    const int cc = blockIdx.x;                // 0..7
    const int n = blockIdx.y * 4 + (threadIdx.x >> 6);
    const int lane = threadIdx.x & 63;
    if (n >= Nn) return;
    const int col = cc * 128 + lane * 2;
    const int head = cc >> 1;
    const int base = row_ptr[n], end = row_ptr[n + 1];
    float a0 = 0.f, a1 = 0.f;
    int e = base;
    for (; e + 2 <= end; e += 2) {
        int s0 = src_csr[e], s1 = src_csr[e + 1];
        float w0 = w[(size_t)e * 4 + head];
        float w1 = w[(size_t)(e + 1) * 4 + head];
        bf16x2 v0 = *(const bf16x2*)(XL + (size_t)s0 * 1024 + col);
        bf16x2 v1 = *(const bf16x2*)(XL + (size_t)s1 * 1024 + col);
        a0 += w0 * (float)v0[0] + w1 * (float)v1[0];
        a1 += w0 * (float)v0[1] + w1 * (float)v1[1];
    }
    if (e < end) {
        int s0 = src_csr[e];
        float w0 = w[(size_t)e * 4 + head];
        bf16x2 v0 = *(const bf16x2*)(XL + (size_t)s0 * 1024 + col);
        a0 += w0 * (float)v0[0];
        a1 += w0 * (float)v0[1];
    }
    size_t o = (size_t)n * 1024 + col;
    bf16x2 sk = *(const bf16x2*)(SK + o);
    bf16x2 res;
    res[0] = (__bf16)(a0 + bias[col] + sb[col] + (float)sk[0]);
    res[1] = (__bf16)(a1 + bias[col + 1] + sb[col + 1] + (float)sk[1]);
    *(bf16x2*)(SK + o) = res;
}

// ------- XCD-sharded aggregation, layer 3 (H=6, C=121, ld=768) + head-mean + bias -------
// grid (8, ceil(Nn/4)); chunk = 96 cols; atomicAdd partial head-means into zeroed out.
__global__ __launch_bounds__(256) void agg_mean2(const __bf16* __restrict__ XL,
                                                 const float* __restrict__ w,
                                                 const int* __restrict__ row_ptr,
                                                 const int* __restrict__ src_csr,
                                                 const float* __restrict__ b3,
                                                 float* __restrict__ out, int Nn) {
    const int cc = blockIdx.x;                // 0..7
    const int n = blockIdx.y * 4 + (threadIdx.x >> 6);
    const int lane = threadIdx.x & 63;
    if (n >= Nn) return;
    int c0 = cc * 96 + lane * 2;              // lanes >= 48 read dummy in-bounds cols
    if (c0 > 764) c0 = 764;
    const int c1 = c0 + 1;
    const bool act = (lane < 48);
    const bool val0 = act && (c0 < 726);
    const bool val1 = act && (c1 < 726);
    const int h0 = val0 ? (c0 / 121) : 0;
    const int h1 = val1 ? (c1 / 121) : 0;
    const int base = row_ptr[n], end = row_ptr[n + 1];
    float a0 = 0.f, a1 = 0.f;
    int e = base;
    for (; e + 2 <= end; e += 2) {
        int s0 = src_csr[e], s1 = src_csr[e + 1];
        const float* wp0 = w + (size_t)e * 6;
        const float* wp1 = w + (size_t)(e + 1) * 6;
        bf16x2 v0 = *(const bf16x2*)(XL + (size_t)s0 * 768 + c0);
        bf16x2 v1 = *(const bf16x2*)(XL + (size_t)s1 * 768 + c0);
        a0 += wp0[h0] * (float)v0[0] + wp1[h0] * (float)v1[0];
        a1 += wp0[h1] * (float)v0[1] + wp1[h1] * (float)v1[1];
    }
    if (e < end) {
        int s0 = src_csr[e];
        const float* wp0 = w + (size_t)e * 6;
        bf16x2 v0 = *(const bf16x2*)(XL + (size_t)s0 * 768 + c0);
        a0 += wp0[h0] * (float)v0[0];
        a1 += wp0[h1] * (float)v0[1];
    }
    // head-mean partials; bias added once by the h==0 contributor of each out column
    if (val0) {
        int j = c0 - h0 * 121;
        float v = a0 * (1.f / 6.f) + (h0 == 0 ? b3[j] : 0.f);
        atomicAdd(&out[(size_t)n * 121 + j], v);
    }
    if (val1) {
        int j = c1 - h1 * 121;
        float v = a1 * (1.f / 6.f) + (h1 == 0 ? b3[j] : 0.f);
        atomicAdd(&out[(size_t)n * 121 + j], v);
    }
}

// ---------------- LayerNorm + ELU (input already = agg + b + skip + sb) ----------------
__global__ __launch_bounds__(256) void ln_elu_k(const __bf16* __restrict__ in,
                                                const float* __restrict__ g,
                                                const float* __restrict__ be,
                                                __bf16* __restrict__ out, int rows_real) {
    const int D = 1024;
    int n = blockIdx.x;
    int t = threadIdx.x;
    size_t ro = (size_t)n * D;
    if (n >= rows_real) {
#pragma unroll
        for (int j = 0; j < 4; j++) out[ro + t + 256 * j] = (__bf16)0.f;
        return;
    }
    float v[4];
    float s = 0.f, q = 0.f;
#pragma unroll
    for (int j = 0; j < 4; j++) {
        int c = t + 256 * j;
        float a = (float)in[ro + c];
        v[j] = a;
        s += a;
        q += a * a;
    }
#pragma unroll
    for (int off = 32; off; off >>= 1) {
        s += __shfl_down(s, off);
        q += __shfl_down(q, off);
    }
    __shared__ float rs[8];
    int wid = t >> 6;
    if ((t & 63) == 0) { rs[wid] = s; rs[wid + 4] = q; }
    __syncthreads();
    s = rs[0] + rs[1] + rs[2] + rs[3];
    q = rs[4] + rs[5] + rs[6] + rs[7];
    float mu = s * (1.f / 1024.f);
    float var = q * (1.f / 1024.f) - mu * mu;
    float inv = rsqrtf(fmaxf(var, 0.f) + 1e-5f);
#pragma unroll
    for (int j = 0; j < 4; j++) {
        int c = t + 256 * j;
        float y = (v[j] - mu) * inv * g[c] + be[c];
        y = y > 0.f ? y : expm1f(y);
        out[ro + c] = (__bf16)y;
    }
}

extern "C" void kernel_launch(void* const* d_in, const int* in_sizes, int n_in,
                              void* d_out, int out_size, void* d_ws, size_t ws_size,
                              hipStream_t stream) {
    const float* x   = (const float*)d_in[0];
    const int*   ei  = (const int*)d_in[1];
    const float* W1  = (const float*)d_in[2];
    const float* as1 = (const float*)d_in[3];
    const float* ad1 = (const float*)d_in[4];
    const float* b1  = (const float*)d_in[5];
    const float* W2  = (const float*)d_in[6];
    const float* as2 = (const float*)d_in[7];
    const float* ad2 = (const float*)d_in[8];
    const float* b2  = (const float*)d_in[9];
    const float* W3  = (const float*)d_in[10];
    const float* as3 = (const float*)d_in[11];
    const float* ad3 = (const float*)d_in[12];
    const float* b3  = (const float*)d_in[13];
    const float* sW1 = (const float*)d_in[14];
    const float* sb1 = (const float*)d_in[15];
    const float* sW2 = (const float*)d_in[16];
    const float* sb2 = (const float*)d_in[17];
    const float* g1  = (const float*)d_in[18];
    const float* be1 = (const float*)d_in[19];
    const float* g2  = (const float*)d_in[20];
    const float* be2 = (const float*)d_in[21];
    float* out = (float*)d_out;

    const int Nn = 20000;
    const int E = in_sizes[1] / 2;     // 320000
    const int E2 = E + Nn;             // 340000
    const int Mpad = 20096;            // 157*128

    char* p = (char*)d_ws;
    auto alloc = [&](size_t bytes) {
        char* r = p;
        p += (bytes + 255) & ~(size_t)255;
        return r;
    };
    __bf16* W1pT  = (__bf16*)alloc((size_t)1024 * 64 * 2);
    __bf16* sW1T  = (__bf16*)alloc((size_t)1024 * 64 * 2);
    __bf16* W2T   = (__bf16*)alloc((size_t)1024 * 1024 * 2);
    __bf16* sW2T  = (__bf16*)alloc((size_t)1024 * 1024 * 2);
    __bf16* W3pT  = (__bf16*)alloc((size_t)768 * 1024 * 2);
    __bf16* xp    = (__bf16*)alloc((size_t)Mpad * 64 * 2);
    __bf16* XL    = (__bf16*)alloc((size_t)Mpad * 1024 * 2);
    __bf16* SK    = (__bf16*)alloc((size_t)Mpad * 1024 * 2);
    __bf16* H1    = (__bf16*)alloc((size_t)Mpad * 1024 * 2);
    float*  asrcb = (float*)alloc((size_t)Nn * 6 * 4);
    float*  adstb = (float*)alloc((size_t)Nn * 6 * 4);
    float*  wbuf  = (float*)alloc((size_t)E2 * 6 * 4);
    int*    rowp  = (int*)alloc((size_t)(Nn + 1) * 4);
    int*    cnt   = (int*)alloc((size_t)Nn * 4);
    int*    scsr  = (int*)alloc((size_t)E2 * 4);
    int*    eiflag= (int*)alloc(256);
    (void)ws_size; (void)n_in; (void)out_size;

    // ---- prep: fp32 -> bf16 packing / transposes ----
    pack_x_k<<<(Mpad * 64) / 256, 256, 0, stream>>>(x, xp, Nn);
    transpose_pad_k<<<dim3(32, 2), 256, 0, stream>>>(W1, W1pT, 50, 1024, 64, 1024);
    transpose_pad_k<<<dim3(32, 2), 256, 0, stream>>>(sW1, sW1T, 50, 1024, 64, 1024);
    transpose_pad_k<<<dim3(32, 32), 256, 0, stream>>>(W2, W2T, 1024, 1024, 1024, 1024);
    transpose_pad_k<<<dim3(32, 32), 256, 0, stream>>>(sW2, sW2T, 1024, 1024, 1024, 1024);
    transpose_pad_k<<<dim3(24, 32), 256, 0, stream>>>(W3, W3pT, 1024, 726, 1024, 768);

    // ---- CSR ----
    probe_ei_k<<<1, 64, 0, stream>>>(ei, eiflag);
    hipMemsetAsync(cnt, 0, (size_t)Nn * 4, stream);
    hist_k<<<(E2 + 255) / 256, 256, 0, stream>>>(ei, eiflag, cnt, E, Nn);
    scan_k<<<1, 1024, 0, stream>>>(cnt, rowp, Nn, E2);
    hipMemsetAsync(cnt, 0, (size_t)Nn * 4, stream);
    fill_csr_k<<<(E2 + 255) / 256, 256, 0, stream>>>(ei, eiflag, rowp, cnt, scsr, E, Nn);

    // ---- layer 1: 50 -> 4x256 concat ----
    gemm_bt<<<dim3(Mpad / 128, 8), 256, 0, stream>>>(xp, W1pT, XL, Mpad, 1024, 64);
    gemm_bt<<<dim3(Mpad / 128, 8), 256, 0, stream>>>(xp, sW1T, SK, Mpad, 1024, 64);
    alpha_k<<<(Nn * 4 * 64) / 256, 256, 0, stream>>>(XL, 1024, as1, ad1, asrcb, adstb, Nn, 4, 256, 256);
    attn_k<<<(Nn + 3) / 4, 256, 0, stream>>>(rowp, scsr, asrcb, adstb, wbuf, Nn, 4);
    agg_skip2<<<dim3(8, (Nn + 3) / 4), 256, 0, stream>>>(XL, wbuf, rowp, scsr, b1, sb1, SK, Nn);
    ln_elu_k<<<Mpad, 256, 0, stream>>>(SK, g1, be1, H1, Nn);

    // ---- layer 2: 1024 -> 4x256 concat ----
    gemm_bt<<<dim3(Mpad / 128, 8), 256, 0, stream>>>(H1, W2T, XL, Mpad, 1024, 1024);
    gemm_bt<<<dim3(Mpad / 128, 8), 256, 0, stream>>>(H1, sW2T, SK, Mpad, 1024, 1024);
    alpha_k<<<(Nn * 4 * 64) / 256, 256, 0, stream>>>(XL, 1024, as2, ad2, asrcb, adstb, Nn, 4, 256, 256);
    attn_k<<<(Nn + 3) / 4, 256, 0, stream>>>(rowp, scsr, asrcb, adstb, wbuf, Nn, 4);
    agg_skip2<<<dim3(8, (Nn + 3) / 4), 256, 0, stream>>>(XL, wbuf, rowp, scsr, b2, sb2, SK, Nn);
    ln_elu_k<<<Mpad, 256, 0, stream>>>(SK, g2, be2, H1, Nn);  // H1 := h2

    // ---- layer 3: 1024 -> 6x121, mean over heads ----
    gemm_bt<<<dim3(Mpad / 128, 6), 256, 0, stream>>>(H1, W3pT, XL, Mpad, 768, 1024);
    alpha_k<<<(Nn * 6 * 64) / 256, 256, 0, stream>>>(XL, 768, as3, ad3, asrcb, adstb, Nn, 6, 121, 121);
    attn_k<<<(Nn + 3) / 4, 256, 0, stream>>>(rowp, scsr, asrcb, adstb, wbuf, Nn, 6);
    hipMemsetAsync(out, 0, (size_t)Nn * 121 * 4, stream);
    agg_mean2<<<dim3(8, (Nn + 3) / 4), 256, 0, stream>>>(XL, wbuf, rowp, scsr, b3, out, Nn);
}

// Round 5
// 869.567 us; speedup vs baseline: 1.2620x; 1.2620x over previous
//
#include <hip/hip_runtime.h>
#include <hip/hip_bf16.h>
#include <math.h>

typedef __attribute__((ext_vector_type(8))) __bf16 bf16x8;
typedef __attribute__((ext_vector_type(2))) __bf16 bf16x2;
typedef __attribute__((ext_vector_type(4))) float f32x4;

#define LSTR 40   // LDS row stride (elements), pads 32-wide K tiles to kill bank conflicts

// ---------------- GEMM: C[M,N] = A[M,K] @ Bt[N,K]^T, bf16 in, fp32 accum, bf16 out ----------
__global__ __launch_bounds__(256) void gemm_bt(const __bf16* __restrict__ A,
                                               const __bf16* __restrict__ Bt,
                                               __bf16* __restrict__ C,
                                               int M, int N, int K) {
    __shared__ __bf16 As[128 * LSTR];
    __shared__ __bf16 Bs[128 * LSTR];
    const int t = threadIdx.x;
    const int lane = t & 63;
    const int wid = t >> 6;
    const int wm = (wid >> 1) << 6;
    const int wn = (wid & 1) << 6;
    const int bm = blockIdx.x * 128;
    const int bn = blockIdx.y * 128;

    const int lr = t >> 2;        // 0..63
    const int lc = (t & 3) << 3;  // 0,8,16,24

    f32x4 acc[4][4];
#pragma unroll
    for (int i = 0; i < 4; i++)
#pragma unroll
        for (int j = 0; j < 4; j++) acc[i][j] = (f32x4){0.f, 0.f, 0.f, 0.f};

    const int m16 = lane & 15;
    const int k8 = (lane >> 4) << 3;

    for (int k0 = 0; k0 < K; k0 += 32) {
        bf16x8 a0 = *(const bf16x8*)(A + (size_t)(bm + lr) * K + k0 + lc);
        bf16x8 a1 = *(const bf16x8*)(A + (size_t)(bm + lr + 64) * K + k0 + lc);
        bf16x8 b0 = *(const bf16x8*)(Bt + (size_t)(bn + lr) * K + k0 + lc);
        bf16x8 b1 = *(const bf16x8*)(Bt + (size_t)(bn + lr + 64) * K + k0 + lc);
        __syncthreads();
        *(bf16x8*)(As + lr * LSTR + lc) = a0;
        *(bf16x8*)(As + (lr + 64) * LSTR + lc) = a1;
        *(bf16x8*)(Bs + lr * LSTR + lc) = b0;
        *(bf16x8*)(Bs + (lr + 64) * LSTR + lc) = b1;
        __syncthreads();
        bf16x8 af[4], bfr[4];
#pragma unroll
        for (int i = 0; i < 4; i++) {
            af[i] = *(const bf16x8*)(As + (wm + 16 * i + m16) * LSTR + k8);
            bfr[i] = *(const bf16x8*)(Bs + (wn + 16 * i + m16) * LSTR + k8);
        }
#pragma unroll
        for (int i = 0; i < 4; i++)
#pragma unroll
            for (int j = 0; j < 4; j++)
                acc[i][j] = __builtin_amdgcn_mfma_f32_16x16x32_bf16(af[i], bfr[j], acc[i][j], 0, 0, 0);
    }
    const int r4 = (lane >> 4) << 2;
#pragma unroll
    for (int i = 0; i < 4; i++) {
#pragma unroll
        for (int j = 0; j < 4; j++) {
            int col = bn + wn + 16 * j + m16;
#pragma unroll
            for (int r = 0; r < 4; r++) {
                int row = bm + wm + 16 * i + r4 + r;
                C[(size_t)row * N + col] = (__bf16)acc[i][j][r];
            }
        }
    }
}

// ---------------- x (fp32) -> padded bf16 [Mpad,64], zeros outside ----------------
__global__ void pack_x_k(const float* __restrict__ x, __bf16* __restrict__ xp, int rows_real) {
    int i = blockIdx.x * 256 + threadIdx.x;
    int n = i >> 6, c = i & 63;
    float v = 0.f;
    if (n < rows_real && c < 50) v = x[n * 50 + c];
    xp[(size_t)n * 64 + c] = (__bf16)v;
}

// ---------------- transpose+pad: W[K,N] fp32 -> WT[Np,Kp] bf16 (zeros outside) -----------
__global__ void transpose_pad_k(const float* __restrict__ W, __bf16* __restrict__ WT,
                                int K, int N, int Kp, int Np) {
    __shared__ float tile[32][33];
    int bx = blockIdx.x, by = blockIdx.y;
    int tx = threadIdx.x & 31, ty = threadIdx.x >> 5;  // 32 x 8
#pragma unroll
    for (int r = ty; r < 32; r += 8) {
        int k = by * 32 + r, n = bx * 32 + tx;
        float v = 0.f;
        if (k < K && n < N) v = W[(size_t)k * N + n];
        tile[r][tx] = v;
    }
    __syncthreads();
#pragma unroll
    for (int r = ty; r < 32; r += 8) {
        int n = bx * 32 + r, k = by * 32 + tx;
        if (n < Np && k < Kp) WT[(size_t)n * Kp + k] = (__bf16)tile[tx][r];
    }
}

// ---------------- edge_index dtype probe: 1 if int64 (odd int32 slots all zero) -----------
__global__ void probe_ei_k(const int* __restrict__ ei, int* __restrict__ flag) {
    if (blockIdx.x == 0 && threadIdx.x == 0) {
        int all0 = 1;
        for (int i = 0; i < 64; i++)
            if (ei[2 * i + 1] != 0) { all0 = 0; break; }
        *flag = all0;
    }
}

__device__ __forceinline__ int load_ei(const int* ei, int idx, int is64) {
    return is64 ? ei[2 * idx] : ei[idx];
}

// ---------------- CSR build (by dst, self-loops appended) ----------------
__global__ void hist_k(const int* __restrict__ ei, const int* __restrict__ flag,
                       int* __restrict__ cnt, int E, int Nn) {
    int e = blockIdx.x * 256 + threadIdx.x;
    if (e >= E + Nn) return;
    int is64 = *flag;
    int d = (e < E) ? load_ei(ei, E + e, is64) : (e - E);
    d = min(max(d, 0), Nn - 1);
    atomicAdd(&cnt[d], 1);
}

__global__ __launch_bounds__(1024) void scan_k(const int* __restrict__ cnt, int* __restrict__ row_ptr,
                                               int Nn, int total) {
    __shared__ int part[1024];
    int t = threadIdx.x;
    int chunk = (Nn + 1023) >> 10;
    int lo = t * chunk;
    int hi = lo + chunk; if (hi > Nn) hi = Nn; if (lo > Nn) lo = Nn;
    int s = 0;
    for (int i = lo; i < hi; i++) s += cnt[i];
    part[t] = s;
    __syncthreads();
    for (int off = 1; off < 1024; off <<= 1) {
        int v = (t >= off) ? part[t - off] : 0;
        __syncthreads();
        part[t] += v;
        __syncthreads();
    }
    int run = part[t] - s;
    for (int i = lo; i < hi; i++) { row_ptr[i] = run; run += cnt[i]; }
    if (t == 0) row_ptr[Nn] = total;
}

__global__ void fill_csr_k(const int* __restrict__ ei, const int* __restrict__ flag,
                           const int* __restrict__ row_ptr, int* __restrict__ cursor,
                           int* __restrict__ src_csr, int E, int Nn) {
    int e = blockIdx.x * 256 + threadIdx.x;
    if (e >= E + Nn) return;
    int is64 = *flag;
    int d = (e < E) ? load_ei(ei, E + e, is64) : (e - E);
    int s = (e < E) ? load_ei(ei, e, is64) : (e - E);
    d = min(max(d, 0), Nn - 1);
    s = min(max(s, 0), Nn - 1);
    int slot = row_ptr[d] + atomicAdd(&cursor[d], 1);
    src_csr[slot] = s;
}

// ---------------- per-(node,head) attention dots (a vectors fp32) ----------------
__global__ void alpha_k(const __bf16* __restrict__ XL, int ld, const float* __restrict__ a_src,
                        const float* __restrict__ a_dst, float* __restrict__ asrc,
                        float* __restrict__ adst, int Nn, int H, int C, int Cpad) {
    int gw = (blockIdx.x * 256 + threadIdx.x) >> 6;
    int lane = threadIdx.x & 63;
    if (gw >= Nn * H) return;
    int n = gw / H, h = gw - n * H;
    const __bf16* row = XL + (size_t)n * ld + h * Cpad;
    const float* as = a_src + h * C;
    const float* ad = a_dst + h * C;
    float s = 0.f, d = 0.f;
    for (int c = lane; c < C; c += 64) {
        float v = (float)row[c];
        s += v * as[c];
        d += v * ad[c];
    }
#pragma unroll
    for (int off = 32; off; off >>= 1) {
        s += __shfl_down(s, off);
        d += __shfl_down(d, off);
    }
    if (lane == 0) { asrc[n * H + h] = s; adst[n * H + h] = d; }
}

// ---------------- per-node segment softmax -> edge weights (one wave per node) -----------
__global__ void attn_k(const int* __restrict__ row_ptr, const int* __restrict__ src_csr,
                       const float* __restrict__ asrc, const float* __restrict__ adst,
                       float* __restrict__ w, int Nn, int H) {
    int gw = (blockIdx.x * 256 + threadIdx.x) >> 6;
    int lane = threadIdx.x & 63;
    if (gw >= Nn) return;
    int n = gw;
    int base = row_ptr[n], deg = row_ptr[n + 1] - base;
    for (int h = 0; h < H; h++) {
        float ad = adst[n * H + h];
        float m = -1e30f;
        for (int s = lane; s < deg; s += 64) {
            float e = asrc[src_csr[base + s] * H + h] + ad;
            e = e > 0.f ? e : 0.2f * e;
            m = fmaxf(m, e);
        }
#pragma unroll
        for (int off = 1; off < 64; off <<= 1) m = fmaxf(m, __shfl_xor(m, off));
        float sum = 0.f;
        for (int s = lane; s < deg; s += 64) {
            float e = asrc[src_csr[base + s] * H + h] + ad;
            e = e > 0.f ? e : 0.2f * e;
            sum += __expf(e - m);
        }
#pragma unroll
        for (int off = 1; off < 64; off <<= 1) sum += __shfl_xor(sum, off);
        float inv = 1.f / (sum + 1e-16f);
        for (int s = lane; s < deg; s += 64) {
            float e = asrc[src_csr[base + s] * H + h] + ad;
            e = e > 0.f ? e : 0.2f * e;
            w[(size_t)(base + s) * H + h] = __expf(e - m) * inv;
        }
    }
}

// ------- XCD-sharded, high-MLP aggregation, layers 1/2 (H=4, C=256, ld=1024) ----------
// grid (8, ceil(Nn/4)); chunk cc = 128 cols (uniform head = cc>>1).
// wave = node; 4 lane-groups of 16 each load a DIFFERENT edge's 128-col slab via bf16x8
// (16 lanes x 16B = 256B = full chunk), unrolled x2 -> 8 edges / 2KB in flight per wave.
__global__ __launch_bounds__(256) void agg_skip4(const __bf16* __restrict__ XL,
                                                 const float* __restrict__ w,
                                                 const int* __restrict__ row_ptr,
                                                 const int* __restrict__ src_csr,
                                                 const float* __restrict__ bias,
                                                 const float* __restrict__ sb,
                                                 __bf16* __restrict__ SK, int Nn) {
    const int cc = blockIdx.x;                 // 0..7
    const int n = blockIdx.y * 4 + (threadIdx.x >> 6);
    const int lane = threadIdx.x & 63;
    if (n >= Nn) return;
    const int g = lane >> 4;                   // edge group 0..3
    const int p = lane & 15;                   // col position
    const int col = cc * 128 + p * 8;
    const int head = cc >> 1;
    const int base = row_ptr[n], end = row_ptr[n + 1];

    float acc[8];
#pragma unroll
    for (int j = 0; j < 8; j++) acc[j] = 0.f;

    for (int e = base; e < end; e += 8) {
        int ea = e + g, eb = e + g + 4;
        bool va = ea < end, vb = eb < end;
        int sa = va ? src_csr[ea] : src_csr[base];
        int sb2 = vb ? src_csr[eb] : src_csr[base];
        float wa = va ? w[(size_t)ea * 4 + head] : 0.f;
        float wb = vb ? w[(size_t)eb * 4 + head] : 0.f;
        bf16x8 xa = *(const bf16x8*)(XL + (size_t)sa * 1024 + col);
        bf16x8 xb = *(const bf16x8*)(XL + (size_t)sb2 * 1024 + col);
#pragma unroll
        for (int j = 0; j < 8; j++) acc[j] += wa * (float)xa[j] + wb * (float)xb[j];
    }
    // reduce across 4 edge-groups (lane xor 16, 32) - p preserved
#pragma unroll
    for (int j = 0; j < 8; j++) {
        acc[j] += __shfl_xor(acc[j], 16);
        acc[j] += __shfl_xor(acc[j], 32);
    }
    if (lane < 16) {
        size_t o = (size_t)n * 1024 + col;
        bf16x8 sk = *(const bf16x8*)(SK + o);
        bf16x8 res;
#pragma unroll
        for (int j = 0; j < 8; j++)
            res[j] = (__bf16)(acc[j] + bias[col + j] + sb[col + j] + (float)sk[j]);
        *(bf16x8*)(SK + o) = res;
    }
}

// ------- XCD-sharded, high-MLP aggregation, layer 3 (H=6, ld=768): bf16 partials -------
// grid (8, ceil(Nn/4)); chunk cc = 96 cols; lanes p<12 cover 96 cols via bf16x8.
// Per-element head (121 not multiple of 8): vector spans <=2 heads -> two weights + mask.
// Writes bf16 partials to part[n][768]; reduce_mean_k does the head-mean.
__global__ __launch_bounds__(256) void agg_mean4(const __bf16* __restrict__ XL,
                                                 const float* __restrict__ w,
                                                 const int* __restrict__ row_ptr,
                                                 const int* __restrict__ src_csr,
                                                 __bf16* __restrict__ part, int Nn) {
    const int cc = blockIdx.x;
    const int n = blockIdx.y * 4 + (threadIdx.x >> 6);
    const int lane = threadIdx.x & 63;
    if (n >= Nn) return;
    const int g = lane >> 4;
    const int p = lane & 15;
    int col = cc * 96 + p * 8;
    if (col > 760) col = 760;                  // keep bf16x8 in row bounds for idle lanes
    const int h0 = col / 121;
    int h1 = (col + 7) / 121;
    if (h1 > 5) h1 = 5;
    bool hi[8];
#pragma unroll
    for (int j = 0; j < 8; j++) hi[j] = ((col + j) / 121) > h0;
    const int base = row_ptr[n], end = row_ptr[n + 1];

    float acc[8];
#pragma unroll
    for (int j = 0; j < 8; j++) acc[j] = 0.f;

    for (int e = base; e < end; e += 8) {
        int ea = e + g, eb = e + g + 4;
        bool va = ea < end, vb = eb < end;
        int sa = va ? src_csr[ea] : src_csr[base];
        int sb2 = vb ? src_csr[eb] : src_csr[base];
        const float* wpa = w + (size_t)ea * 6;
        const float* wpb = w + (size_t)eb * 6;
        float wa0 = va ? wpa[h0] : 0.f, wa1 = va ? wpa[h1] : 0.f;
        float wb0 = vb ? wpb[h0] : 0.f, wb1 = vb ? wpb[h1] : 0.f;
        bf16x8 xa = *(const bf16x8*)(XL + (size_t)sa * 768 + col);
        bf16x8 xb = *(const bf16x8*)(XL + (size_t)sb2 * 768 + col);
#pragma unroll
        for (int j = 0; j < 8; j++) {
            float wja = hi[j] ? wa1 : wa0;
            float wjb = hi[j] ? wb1 : wb0;
            acc[j] += wja * (float)xa[j] + wjb * (float)xb[j];
        }
    }
#pragma unroll
    for (int j = 0; j < 8; j++) {
        acc[j] += __shfl_xor(acc[j], 16);
        acc[j] += __shfl_xor(acc[j], 32);
    }
    if (lane < 12) {
        size_t o = (size_t)n * 768 + cc * 96 + lane * 8;
        bf16x8 res;
#pragma unroll
        for (int j = 0; j < 8; j++) res[j] = (__bf16)acc[j];
        *(bf16x8*)(part + o) = res;
    }
}

// -------- head-mean over bf16 partials + bias -> fp32 out --------
__global__ __launch_bounds__(128) void reduce_mean_k(const __bf16* __restrict__ part,
                                                     const float* __restrict__ b3,
                                                     float* __restrict__ out, int Nn) {
    int n = blockIdx.x;
    int t = threadIdx.x;
    if (t >= 121) return;
    const __bf16* row = part + (size_t)n * 768;
    float s = 0.f;
#pragma unroll
    for (int h = 0; h < 6; h++) s += (float)row[h * 121 + t];
    out[(size_t)n * 121 + t] = s * (1.f / 6.f) + b3[t];
}

// ---------------- LayerNorm + ELU (input already = agg + b + skip + sb) ----------------
__global__ __launch_bounds__(256) void ln_elu_k(const __bf16* __restrict__ in,
                                                const float* __restrict__ g,
                                                const float* __restrict__ be,
                                                __bf16* __restrict__ out, int rows_real) {
    const int D = 1024;
    int n = blockIdx.x;
    int t = threadIdx.x;
    size_t ro = (size_t)n * D;
    if (n >= rows_real) {
#pragma unroll
        for (int j = 0; j < 4; j++) out[ro + t + 256 * j] = (__bf16)0.f;
        return;
    }
    float v[4];
    float s = 0.f, q = 0.f;
#pragma unroll
    for (int j = 0; j < 4; j++) {
        int c = t + 256 * j;
        float a = (float)in[ro + c];
        v[j] = a;
        s += a;
        q += a * a;
    }
#pragma unroll
    for (int off = 32; off; off >>= 1) {
        s += __shfl_down(s, off);
        q += __shfl_down(q, off);
    }
    __shared__ float rs[8];
    int wid = t >> 6;
    if ((t & 63) == 0) { rs[wid] = s; rs[wid + 4] = q; }
    __syncthreads();
    s = rs[0] + rs[1] + rs[2] + rs[3];
    q = rs[4] + rs[5] + rs[6] + rs[7];
    float mu = s * (1.f / 1024.f);
    float var = q * (1.f / 1024.f) - mu * mu;
    float inv = rsqrtf(fmaxf(var, 0.f) + 1e-5f);
#pragma unroll
    for (int j = 0; j < 4; j++) {
        int c = t + 256 * j;
        float y = (v[j] - mu) * inv * g[c] + be[c];
        y = y > 0.f ? y : expm1f(y);
        out[ro + c] = (__bf16)y;
    }
}

extern "C" void kernel_launch(void* const* d_in, const int* in_sizes, int n_in,
                              void* d_out, int out_size, void* d_ws, size_t ws_size,
                              hipStream_t stream) {
    const float* x   = (const float*)d_in[0];
    const int*   ei  = (const int*)d_in[1];
    const float* W1  = (const float*)d_in[2];
    const float* as1 = (const float*)d_in[3];
    const float* ad1 = (const float*)d_in[4];
    const float* b1  = (const float*)d_in[5];
    const float* W2  = (const float*)d_in[6];
    const float* as2 = (const float*)d_in[7];
    const float* ad2 = (const float*)d_in[8];
    const float* b2  = (const float*)d_in[9];
    const float* W3  = (const float*)d_in[10];
    const float* as3 = (const float*)d_in[11];
    const float* ad3 = (const float*)d_in[12];
    const float* b3  = (const float*)d_in[13];
    const float* sW1 = (const float*)d_in[14];
    const float* sb1 = (const float*)d_in[15];
    const float* sW2 = (const float*)d_in[16];
    const float* sb2 = (const float*)d_in[17];
    const float* g1  = (const float*)d_in[18];
    const float* be1 = (const float*)d_in[19];
    const float* g2  = (const float*)d_in[20];
    const float* be2 = (const float*)d_in[21];
    float* out = (float*)d_out;

    const int Nn = 20000;
    const int E = in_sizes[1] / 2;     // 320000
    const int E2 = E + Nn;             // 340000
    const int Mpad = 20096;            // 157*128

    char* p = (char*)d_ws;
    auto alloc = [&](size_t bytes) {
        char* r = p;
        p += (bytes + 255) & ~(size_t)255;
        return r;
    };
    __bf16* W1pT  = (__bf16*)alloc((size_t)1024 * 64 * 2);
    __bf16* sW1T  = (__bf16*)alloc((size_t)1024 * 64 * 2);
    __bf16* W2T   = (__bf16*)alloc((size_t)1024 * 1024 * 2);
    __bf16* sW2T  = (__bf16*)alloc((size_t)1024 * 1024 * 2);
    __bf16* W3pT  = (__bf16*)alloc((size_t)768 * 1024 * 2);
    __bf16* xp    = (__bf16*)alloc((size_t)Mpad * 64 * 2);
    __bf16* XL    = (__bf16*)alloc((size_t)Mpad * 1024 * 2);
    __bf16* SK    = (__bf16*)alloc((size_t)Mpad * 1024 * 2);
    __bf16* H1    = (__bf16*)alloc((size_t)Mpad * 1024 * 2);
    float*  asrcb = (float*)alloc((size_t)Nn * 6 * 4);
    float*  adstb = (float*)alloc((size_t)Nn * 6 * 4);
    float*  wbuf  = (float*)alloc((size_t)E2 * 6 * 4);
    int*    rowp  = (int*)alloc((size_t)(Nn + 1) * 4);
    int*    cnt   = (int*)alloc((size_t)Nn * 4);
    int*    scsr  = (int*)alloc((size_t)E2 * 4);
    int*    eiflag= (int*)alloc(256);
    __bf16* part  = SK;   // SK is dead by layer 3; reuse as [Nn][768] bf16 partials
    (void)ws_size; (void)n_in; (void)out_size;

    // ---- prep: fp32 -> bf16 packing / transposes ----
    pack_x_k<<<(Mpad * 64) / 256, 256, 0, stream>>>(x, xp, Nn);
    transpose_pad_k<<<dim3(32, 2), 256, 0, stream>>>(W1, W1pT, 50, 1024, 64, 1024);
    transpose_pad_k<<<dim3(32, 2), 256, 0, stream>>>(sW1, sW1T, 50, 1024, 64, 1024);
    transpose_pad_k<<<dim3(32, 32), 256, 0, stream>>>(W2, W2T, 1024, 1024, 1024, 1024);
    transpose_pad_k<<<dim3(32, 32), 256, 0, stream>>>(sW2, sW2T, 1024, 1024, 1024, 1024);
    transpose_pad_k<<<dim3(24, 32), 256, 0, stream>>>(W3, W3pT, 1024, 726, 1024, 768);

    // ---- CSR ----
    probe_ei_k<<<1, 64, 0, stream>>>(ei, eiflag);
    hipMemsetAsync(cnt, 0, (size_t)Nn * 4, stream);
    hist_k<<<(E2 + 255) / 256, 256, 0, stream>>>(ei, eiflag, cnt, E, Nn);
    scan_k<<<1, 1024, 0, stream>>>(cnt, rowp, Nn, E2);
    hipMemsetAsync(cnt, 0, (size_t)Nn * 4, stream);
    fill_csr_k<<<(E2 + 255) / 256, 256, 0, stream>>>(ei, eiflag, rowp, cnt, scsr, E, Nn);

    // ---- layer 1: 50 -> 4x256 concat ----
    gemm_bt<<<dim3(Mpad / 128, 8), 256, 0, stream>>>(xp, W1pT, XL, Mpad, 1024, 64);
    gemm_bt<<<dim3(Mpad / 128, 8), 256, 0, stream>>>(xp, sW1T, SK, Mpad, 1024, 64);
    alpha_k<<<(Nn * 4 * 64) / 256, 256, 0, stream>>>(XL, 1024, as1, ad1, asrcb, adstb, Nn, 4, 256, 256);
    attn_k<<<(Nn + 3) / 4, 256, 0, stream>>>(rowp, scsr, asrcb, adstb, wbuf, Nn, 4);
    agg_skip4<<<dim3(8, (Nn + 3) / 4), 256, 0, stream>>>(XL, wbuf, rowp, scsr, b1, sb1, SK, Nn);
    ln_elu_k<<<Mpad, 256, 0, stream>>>(SK, g1, be1, H1, Nn);

    // ---- layer 2: 1024 -> 4x256 concat ----
    gemm_bt<<<dim3(Mpad / 128, 8), 256, 0, stream>>>(H1, W2T, XL, Mpad, 1024, 1024);
    gemm_bt<<<dim3(Mpad / 128, 8), 256, 0, stream>>>(H1, sW2T, SK, Mpad, 1024, 1024);
    alpha_k<<<(Nn * 4 * 64) / 256, 256, 0, stream>>>(XL, 1024, as2, ad2, asrcb, adstb, Nn, 4, 256, 256);
    attn_k<<<(Nn + 3) / 4, 256, 0, stream>>>(rowp, scsr, asrcb, adstb, wbuf, Nn, 4);
    agg_skip4<<<dim3(8, (Nn + 3) / 4), 256, 0, stream>>>(XL, wbuf, rowp, scsr, b2, sb2, SK, Nn);
    ln_elu_k<<<Mpad, 256, 0, stream>>>(SK, g2, be2, H1, Nn);  // H1 := h2

    // ---- layer 3: 1024 -> 6x121, mean over heads ----
    gemm_bt<<<dim3(Mpad / 128, 6), 256, 0, stream>>>(H1, W3pT, XL, Mpad, 768, 1024);
    alpha_k<<<(Nn * 6 * 64) / 256, 256, 0, stream>>>(XL, 768, as3, ad3, asrcb, adstb, Nn, 6, 121, 121);
    attn_k<<<(Nn + 3) / 4, 256, 0, stream>>>(rowp, scsr, asrcb, adstb, wbuf, Nn, 6);
    agg_mean4<<<dim3(8, (Nn + 3) / 4), 256, 0, stream>>>(XL, wbuf, rowp, scsr, part, Nn);
    reduce_mean_k<<<Nn, 128, 0, stream>>>(part, b3, out, Nn);
}

// Round 6
// 851.159 us; speedup vs baseline: 1.2893x; 1.0216x over previous
//
#include <hip/hip_runtime.h>
#include <hip/hip_bf16.h>
#include <math.h>

typedef __attribute__((ext_vector_type(8))) __bf16 bf16x8;
typedef __attribute__((ext_vector_type(4))) float f32x4;

#if __has_builtin(__builtin_amdgcn_global_load_lds)
#define HAVE_GLD 1
#define GLD16(g, l)                                                                      \
    __builtin_amdgcn_global_load_lds(                                                    \
        (const __attribute__((address_space(1))) unsigned int*)(g),                      \
        (__attribute__((address_space(3))) unsigned int*)(l), 16, 0, 0)
#else
#define HAVE_GLD 0
#endif

// ---------------- GEMM: C[M,N] = A[M,K] @ Bt[N,K]^T, bf16 in, fp32 accum, bf16 out -------
// m97 structure: async global->LDS (16B), unpadded [128][32] tiles, 2-barrier K-loop.
__global__ __launch_bounds__(256) void gemm_bt(const __bf16* __restrict__ A,
                                               const __bf16* __restrict__ Bt,
                                               __bf16* __restrict__ C,
                                               int M, int N, int K) {
    __shared__ __bf16 As[128 * 32];
    __shared__ __bf16 Bs[128 * 32];
    const int t = threadIdx.x;
    const int lane = t & 63;
    const int wid = t >> 6;
    const int wm = (wid >> 1) << 6;
    const int wn = (wid & 1) << 6;
    const int bm = blockIdx.x * 128;
    const int bn = blockIdx.y * 128;

    // staging coords: wave-linear LDS dest = w*1024B + lane*16B
    const int srow = (wid << 4) + (lane >> 2);   // 0..63
    const int scol = (lane & 3) << 3;            // element offset 0,8,16,24

    f32x4 acc[4][4];
#pragma unroll
    for (int i = 0; i < 4; i++)
#pragma unroll
        for (int j = 0; j < 4; j++) acc[i][j] = (f32x4){0.f, 0.f, 0.f, 0.f};

    const int m16 = lane & 15;
    const int k8 = (lane >> 4) << 3;

    for (int k0 = 0; k0 < K; k0 += 32) {
        __syncthreads();  // previous tile fully consumed
#if HAVE_GLD
        GLD16(A + (size_t)(bm + srow) * K + k0 + scol, As + srow * 32 + scol);
        GLD16(A + (size_t)(bm + 64 + srow) * K + k0 + scol, As + (64 + srow) * 32 + scol);
        GLD16(Bt + (size_t)(bn + srow) * K + k0 + scol, Bs + srow * 32 + scol);
        GLD16(Bt + (size_t)(bn + 64 + srow) * K + k0 + scol, Bs + (64 + srow) * 32 + scol);
#else
        {
            bf16x8 a0 = *(const bf16x8*)(A + (size_t)(bm + srow) * K + k0 + scol);
            bf16x8 a1 = *(const bf16x8*)(A + (size_t)(bm + 64 + srow) * K + k0 + scol);
            bf16x8 b0 = *(const bf16x8*)(Bt + (size_t)(bn + srow) * K + k0 + scol);
            bf16x8 b1 = *(const bf16x8*)(Bt + (size_t)(bn + 64 + srow) * K + k0 + scol);
            *(bf16x8*)(As + srow * 32 + scol) = a0;
            *(bf16x8*)(As + (64 + srow) * 32 + scol) = a1;
            *(bf16x8*)(Bs + srow * 32 + scol) = b0;
            *(bf16x8*)(Bs + (64 + srow) * 32 + scol) = b1;
        }
#endif
        __syncthreads();  // staging visible (drains vmcnt)
        bf16x8 af[4], bfr[4];
#pragma unroll
        for (int i = 0; i < 4; i++) {
            af[i] = *(const bf16x8*)(As + (wm + 16 * i + m16) * 32 + k8);
            bfr[i] = *(const bf16x8*)(Bs + (wn + 16 * i + m16) * 32 + k8);
        }
#pragma unroll
        for (int i = 0; i < 4; i++)
#pragma unroll
            for (int j = 0; j < 4; j++)
                acc[i][j] = __builtin_amdgcn_mfma_f32_16x16x32_bf16(af[i], bfr[j], acc[i][j], 0, 0, 0);
    }
    const int r4 = (lane >> 4) << 2;
#pragma unroll
    for (int i = 0; i < 4; i++) {
#pragma unroll
        for (int j = 0; j < 4; j++) {
            int col = bn + wn + 16 * j + m16;
#pragma unroll
            for (int r = 0; r < 4; r++) {
                int row = bm + wm + 16 * i + r4 + r;
                C[(size_t)row * N + col] = (__bf16)acc[i][j][r];
            }
        }
    }
}

// ---------------- x (fp32) -> padded bf16 [Mpad,64], zeros outside ----------------
__global__ void pack_x_k(const float* __restrict__ x, __bf16* __restrict__ xp, int rows_real) {
    int i = blockIdx.x * 256 + threadIdx.x;
    int n = i >> 6, c = i & 63;
    float v = 0.f;
    if (n < rows_real && c < 50) v = x[n * 50 + c];
    xp[(size_t)n * 64 + c] = (__bf16)v;
}

// ---------------- transpose+pad: W[K,N] fp32 -> WT[Np,Kp] bf16 (zeros outside) -----------
__global__ void transpose_pad_k(const float* __restrict__ W, __bf16* __restrict__ WT,
                                int K, int N, int Kp, int Np) {
    __shared__ float tile[32][33];
    int bx = blockIdx.x, by = blockIdx.y;
    int tx = threadIdx.x & 31, ty = threadIdx.x >> 5;  // 32 x 8
#pragma unroll
    for (int r = ty; r < 32; r += 8) {
        int k = by * 32 + r, n = bx * 32 + tx;
        float v = 0.f;
        if (k < K && n < N) v = W[(size_t)k * N + n];
        tile[r][tx] = v;
    }
    __syncthreads();
#pragma unroll
    for (int r = ty; r < 32; r += 8) {
        int n = bx * 32 + r, k = by * 32 + tx;
        if (n < Np && k < Kp) WT[(size_t)n * Kp + k] = (__bf16)tile[tx][r];
    }
}

// -------- W3 [1024,726] -> WT3 [768][1024], out row r = h*128 + c (c<121; pad 0) --------
__global__ void transpose_pad_w3_k(const float* __restrict__ W, __bf16* __restrict__ WT) {
    __shared__ float tile[32][33];
    int bx = blockIdx.x, by = blockIdx.y;     // bx: 24 r-tiles, by: 32 k-tiles
    int tx = threadIdx.x & 31, ty = threadIdx.x >> 5;
    int r0 = bx * 32;
    int h = r0 >> 7;           // 32-blocks never straddle a 128 head boundary
    int c0 = r0 & 127;
#pragma unroll
    for (int r = ty; r < 32; r += 8) {
        int k = by * 32 + r;
        int c = c0 + tx;
        float v = 0.f;
        if (c < 121) v = W[(size_t)k * 726 + h * 121 + c];
        tile[r][tx] = v;
    }
    __syncthreads();
#pragma unroll
    for (int r = ty; r < 32; r += 8) {
        int rr = r0 + r;
        int k = by * 32 + tx;
        WT[(size_t)rr * 1024 + k] = (__bf16)tile[tx][r];
    }
}

// ---------------- edge_index dtype probe: 1 if int64 (odd int32 slots all zero) -----------
__global__ void probe_ei_k(const int* __restrict__ ei, int* __restrict__ flag) {
    if (blockIdx.x == 0 && threadIdx.x == 0) {
        int all0 = 1;
        for (int i = 0; i < 64; i++)
            if (ei[2 * i + 1] != 0) { all0 = 0; break; }
        *flag = all0;
    }
}

__device__ __forceinline__ int load_ei(const int* ei, int idx, int is64) {
    return is64 ? ei[2 * idx] : ei[idx];
}

// ---------------- CSR build (by dst, self-loops appended) ----------------
__global__ void hist_k(const int* __restrict__ ei, const int* __restrict__ flag,
                       int* __restrict__ cnt, int E, int Nn) {
    int e = blockIdx.x * 256 + threadIdx.x;
    if (e >= E + Nn) return;
    int is64 = *flag;
    int d = (e < E) ? load_ei(ei, E + e, is64) : (e - E);
    d = min(max(d, 0), Nn - 1);
    atomicAdd(&cnt[d], 1);
}

__global__ __launch_bounds__(1024) void scan_k(const int* __restrict__ cnt, int* __restrict__ row_ptr,
                                               int Nn, int total) {
    __shared__ int part[1024];
    int t = threadIdx.x;
    int chunk = (Nn + 1023) >> 10;
    int lo = t * chunk;
    int hi = lo + chunk; if (hi > Nn) hi = Nn; if (lo > Nn) lo = Nn;
    int s = 0;
    for (int i = lo; i < hi; i++) s += cnt[i];
    part[t] = s;
    __syncthreads();
    for (int off = 1; off < 1024; off <<= 1) {
        int v = (t >= off) ? part[t - off] : 0;
        __syncthreads();
        part[t] += v;
        __syncthreads();
    }
    int run = part[t] - s;
    for (int i = lo; i < hi; i++) { row_ptr[i] = run; run += cnt[i]; }
    if (t == 0) row_ptr[Nn] = total;
}

__global__ void fill_csr_k(const int* __restrict__ ei, const int* __restrict__ flag,
                           const int* __restrict__ row_ptr, int* __restrict__ cursor,
                           int* __restrict__ src_csr, int E, int Nn) {
    int e = blockIdx.x * 256 + threadIdx.x;
    if (e >= E + Nn) return;
    int is64 = *flag;
    int d = (e < E) ? load_ei(ei, E + e, is64) : (e - E);
    int s = (e < E) ? load_ei(ei, e, is64) : (e - E);
    d = min(max(d, 0), Nn - 1);
    s = min(max(s, 0), Nn - 1);
    int slot = row_ptr[d] + atomicAdd(&cursor[d], 1);
    src_csr[slot] = s;
}

// ---------------- per-(node,head) attention dots (a vectors fp32) ----------------
__global__ void alpha_k(const __bf16* __restrict__ XL, int ld, const float* __restrict__ a_src,
                        const float* __restrict__ a_dst, float* __restrict__ asrc,
                        float* __restrict__ adst, int Nn, int H, int C, int Cpad) {
    int gw = (blockIdx.x * 256 + threadIdx.x) >> 6;
    int lane = threadIdx.x & 63;
    if (gw >= Nn * H) return;
    int n = gw / H, h = gw - n * H;
    const __bf16* row = XL + (size_t)n * ld + h * Cpad;
    const float* as = a_src + h * C;
    const float* ad = a_dst + h * C;
    float s = 0.f, d = 0.f;
    for (int c = lane; c < C; c += 64) {
        float v = (float)row[c];
        s += v * as[c];
        d += v * ad[c];
    }
#pragma unroll
    for (int off = 32; off; off >>= 1) {
        s += __shfl_down(s, off);
        d += __shfl_down(d, off);
    }
    if (lane == 0) { asrc[n * H + h] = s; adst[n * H + h] = d; }
}

// ---------------- per-node segment softmax -> edge weights (one wave per node) -----------
__global__ void attn_k(const int* __restrict__ row_ptr, const int* __restrict__ src_csr,
                       const float* __restrict__ asrc, const float* __restrict__ adst,
                       float* __restrict__ w, int Nn, int H) {
    int gw = (blockIdx.x * 256 + threadIdx.x) >> 6;
    int lane = threadIdx.x & 63;
    if (gw >= Nn) return;
    int n = gw;
    int base = row_ptr[n], deg = row_ptr[n + 1] - base;
    for (int h = 0; h < H; h++) {
        float ad = adst[n * H + h];
        float m = -1e30f;
        for (int s = lane; s < deg; s += 64) {
            float e = asrc[src_csr[base + s] * H + h] + ad;
            e = e > 0.f ? e : 0.2f * e;
            m = fmaxf(m, e);
        }
#pragma unroll
        for (int off = 1; off < 64; off <<= 1) m = fmaxf(m, __shfl_xor(m, off));
        float sum = 0.f;
        for (int s = lane; s < deg; s += 64) {
            float e = asrc[src_csr[base + s] * H + h] + ad;
            e = e > 0.f ? e : 0.2f * e;
            sum += __expf(e - m);
        }
#pragma unroll
        for (int off = 1; off < 64; off <<= 1) sum += __shfl_xor(sum, off);
        float inv = 1.f / (sum + 1e-16f);
        for (int s = lane; s < deg; s += 64) {
            float e = asrc[src_csr[base + s] * H + h] + ad;
            e = e > 0.f ? e : 0.2f * e;
            w[(size_t)(base + s) * H + h] = __expf(e - m) * inv;
        }
    }
}

// ------- XCD-sharded aggregation, layers 1/2 (H=4, C=256, ld=1024), 16 edges/iter ------
__global__ __launch_bounds__(256) void agg_skip5(const __bf16* __restrict__ XL,
                                                 const float* __restrict__ w,
                                                 const int* __restrict__ row_ptr,
                                                 const int* __restrict__ src_csr,
                                                 const float* __restrict__ bias,
                                                 const float* __restrict__ sb,
                                                 __bf16* __restrict__ SK, int Nn) {
    const int cc = blockIdx.x;                 // 0..7
    const int n = blockIdx.y * 4 + (threadIdx.x >> 6);
    const int lane = threadIdx.x & 63;
    if (n >= Nn) return;
    const int g = lane >> 4;                   // edge group 0..3
    const int p = lane & 15;
    const int col = cc * 128 + p * 8;
    const int head = cc >> 1;
    const int base = row_ptr[n], end = row_ptr[n + 1];

    float acc[8];
#pragma unroll
    for (int j = 0; j < 8; j++) acc[j] = 0.f;

    for (int e = base; e < end; e += 16) {
        int sidx[4];
        float wv[4];
#pragma unroll
        for (int s = 0; s < 4; s++) {
            int idx = e + g + 4 * s;
            bool v = idx < end;
            sidx[s] = v ? src_csr[idx] : src_csr[base];
            wv[s] = v ? w[(size_t)idx * 4 + head] : 0.f;
        }
#pragma unroll
        for (int s = 0; s < 4; s++) {
            bf16x8 xv = *(const bf16x8*)(XL + (size_t)sidx[s] * 1024 + col);
#pragma unroll
            for (int j = 0; j < 8; j++) acc[j] += wv[s] * (float)xv[j];
        }
    }
#pragma unroll
    for (int j = 0; j < 8; j++) {
        acc[j] += __shfl_xor(acc[j], 16);
        acc[j] += __shfl_xor(acc[j], 32);
    }
    if (lane < 16) {
        size_t o = (size_t)n * 1024 + col;
        bf16x8 sk = *(const bf16x8*)(SK + o);
        bf16x8 res;
#pragma unroll
        for (int j = 0; j < 8; j++)
            res[j] = (__bf16)(acc[j] + bias[col + j] + sb[col + j] + (float)sk[j]);
        *(bf16x8*)(SK + o) = res;
    }
}

// ------- layer-3 aggregation, head-aligned xl [n][6*128] -> bf16 partials [n][768] ------
// grid (6, ceil(Nn/4)); chunk cc = one head (128 cols) -> uniform weight, no selects.
__global__ __launch_bounds__(256) void agg_mean5(const __bf16* __restrict__ XL,
                                                 const float* __restrict__ w,
                                                 const int* __restrict__ row_ptr,
                                                 const int* __restrict__ src_csr,
                                                 __bf16* __restrict__ part, int Nn) {
    const int cc = blockIdx.x;                 // head 0..5
    const int n = blockIdx.y * 4 + (threadIdx.x >> 6);
    const int lane = threadIdx.x & 63;
    if (n >= Nn) return;
    const int g = lane >> 4;
    const int p = lane & 15;
    const int col = cc * 128 + p * 8;
    const int base = row_ptr[n], end = row_ptr[n + 1];

    float acc[8];
#pragma unroll
    for (int j = 0; j < 8; j++) acc[j] = 0.f;

    for (int e = base; e < end; e += 16) {
        int sidx[4];
        float wv[4];
#pragma unroll
        for (int s = 0; s < 4; s++) {
            int idx = e + g + 4 * s;
            bool v = idx < end;
            sidx[s] = v ? src_csr[idx] : src_csr[base];
            wv[s] = v ? w[(size_t)idx * 6 + cc] : 0.f;
        }
#pragma unroll
        for (int s = 0; s < 4; s++) {
            bf16x8 xv = *(const bf16x8*)(XL + (size_t)sidx[s] * 768 + col);
#pragma unroll
            for (int j = 0; j < 8; j++) acc[j] += wv[s] * (float)xv[j];
        }
    }
#pragma unroll
    for (int j = 0; j < 8; j++) {
        acc[j] += __shfl_xor(acc[j], 16);
        acc[j] += __shfl_xor(acc[j], 32);
    }
    if (lane < 16) {
        size_t o = (size_t)n * 768 + col;
        bf16x8 res;
#pragma unroll
        for (int j = 0; j < 8; j++) res[j] = (__bf16)acc[j];
        *(bf16x8*)(part + o) = res;
    }
}

// -------- head-mean over bf16 partials (head stride 128) + bias -> fp32 out --------
__global__ __launch_bounds__(128) void reduce_mean_k(const __bf16* __restrict__ part,
                                                     const float* __restrict__ b3,
                                                     float* __restrict__ out, int Nn) {
    int n = blockIdx.x;
    int t = threadIdx.x;
    if (t >= 121) return;
    const __bf16* row = part + (size_t)n * 768;
    float s = 0.f;
#pragma unroll
    for (int h = 0; h < 6; h++) s += (float)row[h * 128 + t];
    out[(size_t)n * 121 + t] = s * (1.f / 6.f) + b3[t];
}

// ---------------- LayerNorm + ELU (input already = agg + b + skip + sb) ----------------
__global__ __launch_bounds__(256) void ln_elu_k(const __bf16* __restrict__ in,
                                                const float* __restrict__ g,
                                                const float* __restrict__ be,
                                                __bf16* __restrict__ out, int rows_real) {
    const int D = 1024;
    int n = blockIdx.x;
    int t = threadIdx.x;
    size_t ro = (size_t)n * D;
    if (n >= rows_real) {
#pragma unroll
        for (int j = 0; j < 4; j++) out[ro + t + 256 * j] = (__bf16)0.f;
        return;
    }
    float v[4];
    float s = 0.f, q = 0.f;
#pragma unroll
    for (int j = 0; j < 4; j++) {
        int c = t + 256 * j;
        float a = (float)in[ro + c];
        v[j] = a;
        s += a;
        q += a * a;
    }
#pragma unroll
    for (int off = 32; off; off >>= 1) {
        s += __shfl_down(s, off);
        q += __shfl_down(q, off);
    }
    __shared__ float rs[8];
    int wid = t >> 6;
    if ((t & 63) == 0) { rs[wid] = s; rs[wid + 4] = q; }
    __syncthreads();
    s = rs[0] + rs[1] + rs[2] + rs[3];
    q = rs[4] + rs[5] + rs[6] + rs[7];
    float mu = s * (1.f / 1024.f);
    float var = q * (1.f / 1024.f) - mu * mu;
    float inv = rsqrtf(fmaxf(var, 0.f) + 1e-5f);
#pragma unroll
    for (int j = 0; j < 4; j++) {
        int c = t + 256 * j;
        float y = (v[j] - mu) * inv * g[c] + be[c];
        y = y > 0.f ? y : expm1f(y);
        out[ro + c] = (__bf16)y;
    }
}

extern "C" void kernel_launch(void* const* d_in, const int* in_sizes, int n_in,
                              void* d_out, int out_size, void* d_ws, size_t ws_size,
                              hipStream_t stream) {
    const float* x   = (const float*)d_in[0];
    const int*   ei  = (const int*)d_in[1];
    const float* W1  = (const float*)d_in[2];
    const float* as1 = (const float*)d_in[3];
    const float* ad1 = (const float*)d_in[4];
    const float* b1  = (const float*)d_in[5];
    const float* W2  = (const float*)d_in[6];
    const float* as2 = (const float*)d_in[7];
    const float* ad2 = (const float*)d_in[8];
    const float* b2  = (const float*)d_in[9];
    const float* W3  = (const float*)d_in[10];
    const float* as3 = (const float*)d_in[11];
    const float* ad3 = (const float*)d_in[12];
    const float* b3  = (const float*)d_in[13];
    const float* sW1 = (const float*)d_in[14];
    const float* sb1 = (const float*)d_in[15];
    const float* sW2 = (const float*)d_in[16];
    const float* sb2 = (const float*)d_in[17];
    const float* g1  = (const float*)d_in[18];
    const float* be1 = (const float*)d_in[19];
    const float* g2  = (const float*)d_in[20];
    const float* be2 = (const float*)d_in[21];
    float* out = (float*)d_out;

    const int Nn = 20000;
    const int E = in_sizes[1] / 2;     // 320000
    const int E2 = E + Nn;             // 340000
    const int Mpad = 20096;            // 157*128

    char* p = (char*)d_ws;
    auto alloc = [&](size_t bytes) {
        char* r = p;
        p += (bytes + 255) & ~(size_t)255;
        return r;
    };
    __bf16* W1pT  = (__bf16*)alloc((size_t)1024 * 64 * 2);
    __bf16* sW1T  = (__bf16*)alloc((size_t)1024 * 64 * 2);
    __bf16* W2T   = (__bf16*)alloc((size_t)1024 * 1024 * 2);
    __bf16* sW2T  = (__bf16*)alloc((size_t)1024 * 1024 * 2);
    __bf16* W3pT  = (__bf16*)alloc((size_t)768 * 1024 * 2);
    __bf16* xp    = (__bf16*)alloc((size_t)Mpad * 64 * 2);
    __bf16* XL    = (__bf16*)alloc((size_t)Mpad * 1024 * 2);
    __bf16* SK    = (__bf16*)alloc((size_t)Mpad * 1024 * 2);
    __bf16* H1    = (__bf16*)alloc((size_t)Mpad * 1024 * 2);
    float*  asrcb = (float*)alloc((size_t)Nn * 6 * 4);
    float*  adstb = (float*)alloc((size_t)Nn * 6 * 4);
    float*  wbuf  = (float*)alloc((size_t)E2 * 6 * 4);
    int*    rowp  = (int*)alloc((size_t)(Nn + 1) * 4);
    int*    cnt   = (int*)alloc((size_t)Nn * 4);
    int*    scsr  = (int*)alloc((size_t)E2 * 4);
    int*    eiflag= (int*)alloc(256);
    __bf16* part  = SK;   // SK dead by layer 3; reuse as [Nn][768] bf16 partials
    (void)ws_size; (void)n_in; (void)out_size;

    // ---- prep: fp32 -> bf16 packing / transposes ----
    pack_x_k<<<(Mpad * 64) / 256, 256, 0, stream>>>(x, xp, Nn);
    transpose_pad_k<<<dim3(32, 2), 256, 0, stream>>>(W1, W1pT, 50, 1024, 64, 1024);
    transpose_pad_k<<<dim3(32, 2), 256, 0, stream>>>(sW1, sW1T, 50, 1024, 64, 1024);
    transpose_pad_k<<<dim3(32, 32), 256, 0, stream>>>(W2, W2T, 1024, 1024, 1024, 1024);
    transpose_pad_k<<<dim3(32, 32), 256, 0, stream>>>(sW2, sW2T, 1024, 1024, 1024, 1024);
    transpose_pad_w3_k<<<dim3(24, 32), 256, 0, stream>>>(W3, W3pT);

    // ---- CSR ----
    probe_ei_k<<<1, 64, 0, stream>>>(ei, eiflag);
    hipMemsetAsync(cnt, 0, (size_t)Nn * 4, stream);
    hist_k<<<(E2 + 255) / 256, 256, 0, stream>>>(ei, eiflag, cnt, E, Nn);
    scan_k<<<1, 1024, 0, stream>>>(cnt, rowp, Nn, E2);
    hipMemsetAsync(cnt, 0, (size_t)Nn * 4, stream);
    fill_csr_k<<<(E2 + 255) / 256, 256, 0, stream>>>(ei, eiflag, rowp, cnt, scsr, E, Nn);

    // ---- layer 1: 50 -> 4x256 concat ----
    gemm_bt<<<dim3(Mpad / 128, 8), 256, 0, stream>>>(xp, W1pT, XL, Mpad, 1024, 64);
    gemm_bt<<<dim3(Mpad / 128, 8), 256, 0, stream>>>(xp, sW1T, SK, Mpad, 1024, 64);
    alpha_k<<<(Nn * 4 * 64) / 256, 256, 0, stream>>>(XL, 1024, as1, ad1, asrcb, adstb, Nn, 4, 256, 256);
    attn_k<<<(Nn + 3) / 4, 256, 0, stream>>>(rowp, scsr, asrcb, adstb, wbuf, Nn, 4);
    agg_skip5<<<dim3(8, (Nn + 3) / 4), 256, 0, stream>>>(XL, wbuf, rowp, scsr, b1, sb1, SK, Nn);
    ln_elu_k<<<Mpad, 256, 0, stream>>>(SK, g1, be1, H1, Nn);

    // ---- layer 2: 1024 -> 4x256 concat ----
    gemm_bt<<<dim3(Mpad / 128, 8), 256, 0, stream>>>(H1, W2T, XL, Mpad, 1024, 1024);
    gemm_bt<<<dim3(Mpad / 128, 8), 256, 0, stream>>>(H1, sW2T, SK, Mpad, 1024, 1024);
    alpha_k<<<(Nn * 4 * 64) / 256, 256, 0, stream>>>(XL, 1024, as2, ad2, asrcb, adstb, Nn, 4, 256, 256);
    attn_k<<<(Nn + 3) / 4, 256, 0, stream>>>(rowp, scsr, asrcb, adstb, wbuf, Nn, 4);
    agg_skip5<<<dim3(8, (Nn + 3) / 4), 256, 0, stream>>>(XL, wbuf, rowp, scsr, b2, sb2, SK, Nn);
    ln_elu_k<<<Mpad, 256, 0, stream>>>(SK, g2, be2, H1, Nn);  // H1 := h2

    // ---- layer 3: 1024 -> 6x(121 pad 128), mean over heads ----
    gemm_bt<<<dim3(Mpad / 128, 6), 256, 0, stream>>>(H1, W3pT, XL, Mpad, 768, 1024);
    alpha_k<<<(Nn * 6 * 64) / 256, 256, 0, stream>>>(XL, 768, as3, ad3, asrcb, adstb, Nn, 6, 121, 128);
    attn_k<<<(Nn + 3) / 4, 256, 0, stream>>>(rowp, scsr, asrcb, adstb, wbuf, Nn, 6);
    agg_mean5<<<dim3(6, (Nn + 3) / 4), 256, 0, stream>>>(XL, wbuf, rowp, scsr, part, Nn);
    reduce_mean_k<<<Nn, 128, 0, stream>>>(part, b3, out, Nn);
}

// Round 7
// 839.466 us; speedup vs baseline: 1.3073x; 1.0139x over previous
//
#include <hip/hip_runtime.h>
#include <hip/hip_bf16.h>
#include <math.h>

typedef __attribute__((ext_vector_type(8))) __bf16 bf16x8;
typedef __attribute__((ext_vector_type(4))) float f32x4;
typedef __attribute__((ext_vector_type(4))) int i32x4;

#if __has_builtin(__builtin_amdgcn_global_load_lds)
#define HAVE_GLD 1
#define GLD16(g, l)                                                                      \
    __builtin_amdgcn_global_load_lds(                                                    \
        (const __attribute__((address_space(1))) unsigned int*)(g),                      \
        (__attribute__((address_space(3))) unsigned int*)(l), 16, 0, 0)
#else
#define HAVE_GLD 0
#endif

// ---------------- GEMM: C[M,N] = A[M,K] @ Bt[N,K]^T, bf16 in, fp32 accum, bf16 out -------
__global__ __launch_bounds__(256) void gemm_bt(const __bf16* __restrict__ A,
                                               const __bf16* __restrict__ Bt,
                                               __bf16* __restrict__ C,
                                               int M, int N, int K) {
    __shared__ __bf16 As[128 * 32];
    __shared__ __bf16 Bs[128 * 32];
    const int t = threadIdx.x;
    const int lane = t & 63;
    const int wid = t >> 6;
    const int wm = (wid >> 1) << 6;
    const int wn = (wid & 1) << 6;
    const int bm = blockIdx.x * 128;
    const int bn = blockIdx.y * 128;

    const int srow = (wid << 4) + (lane >> 2);   // 0..63
    const int scol = (lane & 3) << 3;            // 0,8,16,24

    f32x4 acc[4][4];
#pragma unroll
    for (int i = 0; i < 4; i++)
#pragma unroll
        for (int j = 0; j < 4; j++) acc[i][j] = (f32x4){0.f, 0.f, 0.f, 0.f};

    const int m16 = lane & 15;
    const int k8 = (lane >> 4) << 3;

    for (int k0 = 0; k0 < K; k0 += 32) {
        __syncthreads();
#if HAVE_GLD
        GLD16(A + (size_t)(bm + srow) * K + k0 + scol, As + srow * 32 + scol);
        GLD16(A + (size_t)(bm + 64 + srow) * K + k0 + scol, As + (64 + srow) * 32 + scol);
        GLD16(Bt + (size_t)(bn + srow) * K + k0 + scol, Bs + srow * 32 + scol);
        GLD16(Bt + (size_t)(bn + 64 + srow) * K + k0 + scol, Bs + (64 + srow) * 32 + scol);
#else
        {
            bf16x8 a0 = *(const bf16x8*)(A + (size_t)(bm + srow) * K + k0 + scol);
            bf16x8 a1 = *(const bf16x8*)(A + (size_t)(bm + 64 + srow) * K + k0 + scol);
            bf16x8 b0 = *(const bf16x8*)(Bt + (size_t)(bn + srow) * K + k0 + scol);
            bf16x8 b1 = *(const bf16x8*)(Bt + (size_t)(bn + 64 + srow) * K + k0 + scol);
            *(bf16x8*)(As + srow * 32 + scol) = a0;
            *(bf16x8*)(As + (64 + srow) * 32 + scol) = a1;
            *(bf16x8*)(Bs + srow * 32 + scol) = b0;
            *(bf16x8*)(Bs + (64 + srow) * 32 + scol) = b1;
        }
#endif
        __syncthreads();
        bf16x8 af[4], bfr[4];
#pragma unroll
        for (int i = 0; i < 4; i++) {
            af[i] = *(const bf16x8*)(As + (wm + 16 * i + m16) * 32 + k8);
            bfr[i] = *(const bf16x8*)(Bs + (wn + 16 * i + m16) * 32 + k8);
        }
#pragma unroll
        for (int i = 0; i < 4; i++)
#pragma unroll
            for (int j = 0; j < 4; j++)
                acc[i][j] = __builtin_amdgcn_mfma_f32_16x16x32_bf16(af[i], bfr[j], acc[i][j], 0, 0, 0);
    }
    const int r4 = (lane >> 4) << 2;
#pragma unroll
    for (int i = 0; i < 4; i++) {
#pragma unroll
        for (int j = 0; j < 4; j++) {
            int col = bn + wn + 16 * j + m16;
#pragma unroll
            for (int r = 0; r < 4; r++) {
                int row = bm + wm + 16 * i + r4 + r;
                C[(size_t)row * N + col] = (__bf16)acc[i][j][r];
            }
        }
    }
}

// ---------------- x (fp32) -> padded bf16 [Mpad,64], zeros outside ----------------
__global__ void pack_x_k(const float* __restrict__ x, __bf16* __restrict__ xp, int rows_real) {
    int i = blockIdx.x * 256 + threadIdx.x;
    int n = i >> 6, c = i & 63;
    float v = 0.f;
    if (n < rows_real && c < 50) v = x[n * 50 + c];
    xp[(size_t)n * 64 + c] = (__bf16)v;
}

// ---------------- transpose+pad: W[K,N] fp32 -> WT[Np,Kp] bf16 (zeros outside) -----------
__global__ void transpose_pad_k(const float* __restrict__ W, __bf16* __restrict__ WT,
                                int K, int N, int Kp, int Np) {
    __shared__ float tile[32][33];
    int bx = blockIdx.x, by = blockIdx.y;
    int tx = threadIdx.x & 31, ty = threadIdx.x >> 5;
#pragma unroll
    for (int r = ty; r < 32; r += 8) {
        int k = by * 32 + r, n = bx * 32 + tx;
        float v = 0.f;
        if (k < K && n < N) v = W[(size_t)k * N + n];
        tile[r][tx] = v;
    }
    __syncthreads();
#pragma unroll
    for (int r = ty; r < 32; r += 8) {
        int n = bx * 32 + r, k = by * 32 + tx;
        if (n < Np && k < Kp) WT[(size_t)n * Kp + k] = (__bf16)tile[tx][r];
    }
}

// -------- W3 [1024,726] -> WT3 [768][1024], out row r = h*128 + c (c<121; pad 0) --------
__global__ void transpose_pad_w3_k(const float* __restrict__ W, __bf16* __restrict__ WT) {
    __shared__ float tile[32][33];
    int bx = blockIdx.x, by = blockIdx.y;
    int tx = threadIdx.x & 31, ty = threadIdx.x >> 5;
    int r0 = bx * 32;
    int h = r0 >> 7;
    int c0 = r0 & 127;
#pragma unroll
    for (int r = ty; r < 32; r += 8) {
        int k = by * 32 + r;
        int c = c0 + tx;
        float v = 0.f;
        if (c < 121) v = W[(size_t)k * 726 + h * 121 + c];
        tile[r][tx] = v;
    }
    __syncthreads();
#pragma unroll
    for (int r = ty; r < 32; r += 8) {
        int rr = r0 + r;
        int k = by * 32 + tx;
        WT[(size_t)rr * 1024 + k] = (__bf16)tile[tx][r];
    }
}

// ---------------- edge_index dtype probe ----------------
__global__ void probe_ei_k(const int* __restrict__ ei, int* __restrict__ flag) {
    if (blockIdx.x == 0 && threadIdx.x == 0) {
        int all0 = 1;
        for (int i = 0; i < 64; i++)
            if (ei[2 * i + 1] != 0) { all0 = 0; break; }
        *flag = all0;
    }
}

__device__ __forceinline__ int load_ei(const int* ei, int idx, int is64) {
    return is64 ? ei[2 * idx] : ei[idx];
}

// ---------------- CSR build (by dst, self-loops appended, degree padded to x16) ----------
__global__ void hist_k(const int* __restrict__ ei, const int* __restrict__ flag,
                       int* __restrict__ cnt, int E, int Nn) {
    int e = blockIdx.x * 256 + threadIdx.x;
    if (e >= E + Nn) return;
    int is64 = *flag;
    int d = (e < E) ? load_ei(ei, E + e, is64) : (e - E);
    d = min(max(d, 0), Nn - 1);
    atomicAdd(&cnt[d], 1);
}

// scan over PADDED counts: rowp[i+1]-rowp[i] = 16*ceil(cnt[i]/16)
__global__ __launch_bounds__(1024) void scan_k(const int* __restrict__ cnt, int* __restrict__ row_ptr,
                                               int Nn) {
    __shared__ int part[1024];
    int t = threadIdx.x;
    int chunk = (Nn + 1023) >> 10;
    int lo = t * chunk;
    int hi = lo + chunk; if (hi > Nn) hi = Nn; if (lo > Nn) lo = Nn;
    int s = 0;
    for (int i = lo; i < hi; i++) s += (cnt[i] + 15) & ~15;
    part[t] = s;
    __syncthreads();
    for (int off = 1; off < 1024; off <<= 1) {
        int v = (t >= off) ? part[t - off] : 0;
        __syncthreads();
        part[t] += v;
        __syncthreads();
    }
    int run = part[t] - s;
    for (int i = lo; i < hi; i++) { row_ptr[i] = run; run += (cnt[i] + 15) & ~15; }
    if (t == 1023) row_ptr[Nn] = part[1023];
}

__global__ void fill_csr_k(const int* __restrict__ ei, const int* __restrict__ flag,
                           const int* __restrict__ row_ptr, int* __restrict__ cursor,
                           int* __restrict__ src_csr, int E, int Nn) {
    int e = blockIdx.x * 256 + threadIdx.x;
    if (e >= E + Nn) return;
    int is64 = *flag;
    int d = (e < E) ? load_ei(ei, E + e, is64) : (e - E);
    int s = (e < E) ? load_ei(ei, e, is64) : (e - E);
    d = min(max(d, 0), Nn - 1);
    s = min(max(s, 0), Nn - 1);
    int slot = row_ptr[d] + atomicAdd(&cursor[d], 1);
    src_csr[slot] = s;
}

// ---------------- per-(node,head) attention dots ----------------
__global__ void alpha_k(const __bf16* __restrict__ XL, int ld, const float* __restrict__ a_src,
                        const float* __restrict__ a_dst, float* __restrict__ asrc,
                        float* __restrict__ adst, int Nn, int H, int C, int Cpad) {
    int gw = (blockIdx.x * 256 + threadIdx.x) >> 6;
    int lane = threadIdx.x & 63;
    if (gw >= Nn * H) return;
    int n = gw / H, h = gw - n * H;
    const __bf16* row = XL + (size_t)n * ld + h * Cpad;
    const float* as = a_src + h * C;
    const float* ad = a_dst + h * C;
    float s = 0.f, d = 0.f;
    for (int c = lane; c < C; c += 64) {
        float v = (float)row[c];
        s += v * as[c];
        d += v * ad[c];
    }
#pragma unroll
    for (int off = 32; off; off >>= 1) {
        s += __shfl_down(s, off);
        d += __shfl_down(d, off);
    }
    if (lane == 0) { asrc[n * H + h] = s; adst[n * H + h] = d; }
}

// ------- per-node segment softmax -> transposed edge weights wt[h][Epad] ----------
// real degree from deg[]; padded slots stay 0 (memset).
__global__ void attn_k(const int* __restrict__ row_ptr, const int* __restrict__ deg,
                       const int* __restrict__ src_csr,
                       const float* __restrict__ asrc, const float* __restrict__ adst,
                       float* __restrict__ wt, int Nn, int H, int Epad) {
    int gw = (blockIdx.x * 256 + threadIdx.x) >> 6;
    int lane = threadIdx.x & 63;
    if (gw >= Nn) return;
    int n = gw;
    int base = row_ptr[n], dg = deg[n];
    for (int h = 0; h < H; h++) {
        float ad = adst[n * H + h];
        float m = -1e30f;
        for (int s = lane; s < dg; s += 64) {
            float e = asrc[src_csr[base + s] * H + h] + ad;
            e = e > 0.f ? e : 0.2f * e;
            m = fmaxf(m, e);
        }
#pragma unroll
        for (int off = 1; off < 64; off <<= 1) m = fmaxf(m, __shfl_xor(m, off));
        float sum = 0.f;
        for (int s = lane; s < dg; s += 64) {
            float e = asrc[src_csr[base + s] * H + h] + ad;
            e = e > 0.f ? e : 0.2f * e;
            sum += __expf(e - m);
        }
#pragma unroll
        for (int off = 1; off < 64; off <<= 1) sum += __shfl_xor(sum, off);
        float inv = 1.f / (sum + 1e-16f);
        float* wrow = wt + (size_t)h * Epad;
        for (int s = lane; s < dg; s += 64) {
            float e = asrc[src_csr[base + s] * H + h] + ad;
            e = e > 0.f ? e : 0.2f * e;
            wrow[base + s] = __expf(e - m) * inv;
        }
    }
}

// ------- XCD-sharded aggregation, layers 1/2 (H=4, C=256, ld=1024) ----------
// Padded CSR: no bounds checks. Group g = 4 contiguous edges -> int4/float4 meta loads.
__global__ __launch_bounds__(256) void agg_skip6(const __bf16* __restrict__ XL,
                                                 const float* __restrict__ wt,
                                                 const int* __restrict__ row_ptr,
                                                 const int* __restrict__ src_csr,
                                                 const float* __restrict__ bias,
                                                 const float* __restrict__ sb,
                                                 __bf16* __restrict__ SK, int Nn, int Epad) {
    const int cc = blockIdx.x;                 // 0..7
    const int n = blockIdx.y * 4 + (threadIdx.x >> 6);
    const int lane = threadIdx.x & 63;
    if (n >= Nn) return;
    const int g = lane >> 4;
    const int p = lane & 15;
    const int col = cc * 128 + p * 8;
    const float* wrow = wt + (size_t)(cc >> 1) * Epad;
    const __bf16* XLc = XL + col;
    const int base = row_ptr[n], end = row_ptr[n + 1];

    float acc[8];
#pragma unroll
    for (int j = 0; j < 8; j++) acc[j] = 0.f;

    for (int e = base; e < end; e += 16) {
        i32x4 si = *(const i32x4*)(src_csr + e + 4 * g);
        f32x4 wv = *(const f32x4*)(wrow + e + 4 * g);
#pragma unroll
        for (int s = 0; s < 4; s++) {
            bf16x8 xv = *(const bf16x8*)(XLc + (size_t)si[s] * 1024);
#pragma unroll
            for (int j = 0; j < 8; j++) acc[j] += wv[s] * (float)xv[j];
        }
    }
#pragma unroll
    for (int j = 0; j < 8; j++) {
        acc[j] += __shfl_xor(acc[j], 16);
        acc[j] += __shfl_xor(acc[j], 32);
    }
    if (lane < 16) {
        size_t o = (size_t)n * 1024 + col;
        bf16x8 sk = *(const bf16x8*)(SK + o);
        bf16x8 res;
#pragma unroll
        for (int j = 0; j < 8; j++)
            res[j] = (__bf16)(acc[j] + bias[col + j] + sb[col + j] + (float)sk[j]);
        *(bf16x8*)(SK + o) = res;
    }
}

// ------- layer-3 aggregation, head-aligned xl [n][6*128] -> bf16 partials [n][768] ------
__global__ __launch_bounds__(256) void agg_mean6(const __bf16* __restrict__ XL,
                                                 const float* __restrict__ wt,
                                                 const int* __restrict__ row_ptr,
                                                 const int* __restrict__ src_csr,
                                                 __bf16* __restrict__ part, int Nn, int Epad) {
    const int cc = blockIdx.x;                 // head 0..5
    const int n = blockIdx.y * 4 + (threadIdx.x >> 6);
    const int lane = threadIdx.x & 63;
    if (n >= Nn) return;
    const int g = lane >> 4;
    const int p = lane & 15;
    const int col = cc * 128 + p * 8;
    const float* wrow = wt + (size_t)cc * Epad;
    const __bf16* XLc = XL + col;
    const int base = row_ptr[n], end = row_ptr[n + 1];

    float acc[8];
#pragma unroll
    for (int j = 0; j < 8; j++) acc[j] = 0.f;

    for (int e = base; e < end; e += 16) {
        i32x4 si = *(const i32x4*)(src_csr + e + 4 * g);
        f32x4 wv = *(const f32x4*)(wrow + e + 4 * g);
#pragma unroll
        for (int s = 0; s < 4; s++) {
            bf16x8 xv = *(const bf16x8*)(XLc + (size_t)si[s] * 768);
#pragma unroll
            for (int j = 0; j < 8; j++) acc[j] += wv[s] * (float)xv[j];
        }
    }
#pragma unroll
    for (int j = 0; j < 8; j++) {
        acc[j] += __shfl_xor(acc[j], 16);
        acc[j] += __shfl_xor(acc[j], 32);
    }
    if (lane < 16) {
        size_t o = (size_t)n * 768 + col;
        bf16x8 res;
#pragma unroll
        for (int j = 0; j < 8; j++) res[j] = (__bf16)acc[j];
        *(bf16x8*)(part + o) = res;
    }
}

// -------- head-mean over bf16 partials (head stride 128) + bias -> fp32 out --------
__global__ __launch_bounds__(128) void reduce_mean_k(const __bf16* __restrict__ part,
                                                     const float* __restrict__ b3,
                                                     float* __restrict__ out, int Nn) {
    int n = blockIdx.x;
    int t = threadIdx.x;
    if (t >= 121) return;
    const __bf16* row = part + (size_t)n * 768;
    float s = 0.f;
#pragma unroll
    for (int h = 0; h < 6; h++) s += (float)row[h * 128 + t];
    out[(size_t)n * 121 + t] = s * (1.f / 6.f) + b3[t];
}

// ---------------- LayerNorm + ELU ----------------
__global__ __launch_bounds__(256) void ln_elu_k(const __bf16* __restrict__ in,
                                                const float* __restrict__ g,
                                                const float* __restrict__ be,
                                                __bf16* __restrict__ out, int rows_real) {
    const int D = 1024;
    int n = blockIdx.x;
    int t = threadIdx.x;
    size_t ro = (size_t)n * D;
    if (n >= rows_real) {
#pragma unroll
        for (int j = 0; j < 4; j++) out[ro + t + 256 * j] = (__bf16)0.f;
        return;
    }
    float v[4];
    float s = 0.f, q = 0.f;
#pragma unroll
    for (int j = 0; j < 4; j++) {
        int c = t + 256 * j;
        float a = (float)in[ro + c];
        v[j] = a;
        s += a;
        q += a * a;
    }
#pragma unroll
    for (int off = 32; off; off >>= 1) {
        s += __shfl_down(s, off);
        q += __shfl_down(q, off);
    }
    __shared__ float rs[8];
    int wid = t >> 6;
    if ((t & 63) == 0) { rs[wid] = s; rs[wid + 4] = q; }
    __syncthreads();
    s = rs[0] + rs[1] + rs[2] + rs[3];
    q = rs[4] + rs[5] + rs[6] + rs[7];
    float mu = s * (1.f / 1024.f);
    float var = q * (1.f / 1024.f) - mu * mu;
    float inv = rsqrtf(fmaxf(var, 0.f) + 1e-5f);
#pragma unroll
    for (int j = 0; j < 4; j++) {
        int c = t + 256 * j;
        float y = (v[j] - mu) * inv * g[c] + be[c];
        y = y > 0.f ? y : expm1f(y);
        out[ro + c] = (__bf16)y;
    }
}

extern "C" void kernel_launch(void* const* d_in, const int* in_sizes, int n_in,
                              void* d_out, int out_size, void* d_ws, size_t ws_size,
                              hipStream_t stream) {
    const float* x   = (const float*)d_in[0];
    const int*   ei  = (const int*)d_in[1];
    const float* W1  = (const float*)d_in[2];
    const float* as1 = (const float*)d_in[3];
    const float* ad1 = (const float*)d_in[4];
    const float* b1  = (const float*)d_in[5];
    const float* W2  = (const float*)d_in[6];
    const float* as2 = (const float*)d_in[7];
    const float* ad2 = (const float*)d_in[8];
    const float* b2  = (const float*)d_in[9];
    const float* W3  = (const float*)d_in[10];
    const float* as3 = (const float*)d_in[11];
    const float* ad3 = (const float*)d_in[12];
    const float* b3  = (const float*)d_in[13];
    const float* sW1 = (const float*)d_in[14];
    const float* sb1 = (const float*)d_in[15];
    const float* sW2 = (const float*)d_in[16];
    const float* sb2 = (const float*)d_in[17];
    const float* g1  = (const float*)d_in[18];
    const float* be1 = (const float*)d_in[19];
    const float* g2  = (const float*)d_in[20];
    const float* be2 = (const float*)d_in[21];
    float* out = (float*)d_out;

    const int Nn = 20000;
    const int E = in_sizes[1] / 2;         // 320000
    const int E2 = E + Nn;                 // 340000
    const int Ecap = E2 + 16 * Nn;         // padded-CSR capacity (660000)
    const int Mpad = 20096;                // 157*128

    char* p = (char*)d_ws;
    auto alloc = [&](size_t bytes) {
        char* r = p;
        p += (bytes + 255) & ~(size_t)255;
        return r;
    };
    __bf16* W1pT  = (__bf16*)alloc((size_t)1024 * 64 * 2);
    __bf16* sW1T  = (__bf16*)alloc((size_t)1024 * 64 * 2);
    __bf16* W2T   = (__bf16*)alloc((size_t)1024 * 1024 * 2);
    __bf16* sW2T  = (__bf16*)alloc((size_t)1024 * 1024 * 2);
    __bf16* W3pT  = (__bf16*)alloc((size_t)768 * 1024 * 2);
    __bf16* xp    = (__bf16*)alloc((size_t)Mpad * 64 * 2);
    __bf16* XL    = (__bf16*)alloc((size_t)Mpad * 1024 * 2);
    __bf16* SK    = (__bf16*)alloc((size_t)Mpad * 1024 * 2);
    __bf16* H1    = (__bf16*)alloc((size_t)Mpad * 1024 * 2);
    float*  asrcb = (float*)alloc((size_t)Nn * 6 * 4);
    float*  adstb = (float*)alloc((size_t)Nn * 6 * 4);
    float*  wbuf  = (float*)alloc((size_t)6 * Ecap * 4);   // wt[h][Ecap]
    int*    rowp  = (int*)alloc((size_t)(Nn + 1) * 4);
    int*    cnt   = (int*)alloc((size_t)Nn * 4);
    int*    scsr  = (int*)alloc((size_t)Ecap * 4);
    int*    eiflag= (int*)alloc(256);
    __bf16* part  = SK;   // SK dead by layer 3
    (void)ws_size; (void)n_in; (void)out_size;

    // ---- prep: fp32 -> bf16 packing / transposes ----
    pack_x_k<<<(Mpad * 64) / 256, 256, 0, stream>>>(x, xp, Nn);
    transpose_pad_k<<<dim3(32, 2), 256, 0, stream>>>(W1, W1pT, 50, 1024, 64, 1024);
    transpose_pad_k<<<dim3(32, 2), 256, 0, stream>>>(sW1, sW1T, 50, 1024, 64, 1024);
    transpose_pad_k<<<dim3(32, 32), 256, 0, stream>>>(W2, W2T, 1024, 1024, 1024, 1024);
    transpose_pad_k<<<dim3(32, 32), 256, 0, stream>>>(sW2, sW2T, 1024, 1024, 1024, 1024);
    transpose_pad_w3_k<<<dim3(24, 32), 256, 0, stream>>>(W3, W3pT);

    // ---- padded CSR ----
    probe_ei_k<<<1, 64, 0, stream>>>(ei, eiflag);
    hipMemsetAsync(cnt, 0, (size_t)Nn * 4, stream);
    hist_k<<<(E2 + 255) / 256, 256, 0, stream>>>(ei, eiflag, cnt, E, Nn);
    scan_k<<<1, 1024, 0, stream>>>(cnt, rowp, Nn);
    hipMemsetAsync(cnt, 0, (size_t)Nn * 4, stream);
    hipMemsetAsync(scsr, 0, (size_t)Ecap * 4, stream);          // dummy src = 0
    hipMemsetAsync(wbuf, 0, (size_t)6 * Ecap * 4, stream);      // dummy w = 0
    fill_csr_k<<<(E2 + 255) / 256, 256, 0, stream>>>(ei, eiflag, rowp, cnt, scsr, E, Nn);
    // cnt now holds real degrees

    // ---- layer 1: 50 -> 4x256 concat ----
    gemm_bt<<<dim3(Mpad / 128, 8), 256, 0, stream>>>(xp, W1pT, XL, Mpad, 1024, 64);
    gemm_bt<<<dim3(Mpad / 128, 8), 256, 0, stream>>>(xp, sW1T, SK, Mpad, 1024, 64);
    alpha_k<<<(Nn * 4 * 64) / 256, 256, 0, stream>>>(XL, 1024, as1, ad1, asrcb, adstb, Nn, 4, 256, 256);
    attn_k<<<(Nn + 3) / 4, 256, 0, stream>>>(rowp, cnt, scsr, asrcb, adstb, wbuf, Nn, 4, Ecap);
    agg_skip6<<<dim3(8, (Nn + 3) / 4), 256, 0, stream>>>(XL, wbuf, rowp, scsr, b1, sb1, SK, Nn, Ecap);
    ln_elu_k<<<Mpad, 256, 0, stream>>>(SK, g1, be1, H1, Nn);

    // ---- layer 2: 1024 -> 4x256 concat ----
    gemm_bt<<<dim3(Mpad / 128, 8), 256, 0, stream>>>(H1, W2T, XL, Mpad, 1024, 1024);
    gemm_bt<<<dim3(Mpad / 128, 8), 256, 0, stream>>>(H1, sW2T, SK, Mpad, 1024, 1024);
    alpha_k<<<(Nn * 4 * 64) / 256, 256, 0, stream>>>(XL, 1024, as2, ad2, asrcb, adstb, Nn, 4, 256, 256);
    attn_k<<<(Nn + 3) / 4, 256, 0, stream>>>(rowp, cnt, scsr, asrcb, adstb, wbuf, Nn, 4, Ecap);
    agg_skip6<<<dim3(8, (Nn + 3) / 4), 256, 0, stream>>>(XL, wbuf, rowp, scsr, b2, sb2, SK, Nn, Ecap);
    ln_elu_k<<<Mpad, 256, 0, stream>>>(SK, g2, be2, H1, Nn);  // H1 := h2

    // ---- layer 3: 1024 -> 6x(121 pad 128), mean over heads ----
    gemm_bt<<<dim3(Mpad / 128, 6), 256, 0, stream>>>(H1, W3pT, XL, Mpad, 768, 1024);
    alpha_k<<<(Nn * 6 * 64) / 256, 256, 0, stream>>>(XL, 768, as3, ad3, asrcb, adstb, Nn, 6, 121, 128);
    attn_k<<<(Nn + 3) / 4, 256, 0, stream>>>(rowp, cnt, scsr, asrcb, adstb, wbuf, Nn, 6, Ecap);
    agg_mean6<<<dim3(6, (Nn + 3) / 4), 256, 0, stream>>>(XL, wbuf, rowp, scsr, part, Nn, Ecap);
    reduce_mean_k<<<Nn, 128, 0, stream>>>(part, b3, out, Nn);
}

// Round 9
// 797.526 us; speedup vs baseline: 1.3760x; 1.0526x over previous
//
#include <hip/hip_runtime.h>
#include <hip/hip_bf16.h>
#include <math.h>

typedef __attribute__((ext_vector_type(8))) __bf16 bf16x8;
typedef __attribute__((ext_vector_type(4))) float f32x4;

#if __has_builtin(__builtin_amdgcn_global_load_lds)
#define GLD16(g, l)                                                                      \
    __builtin_amdgcn_global_load_lds(                                                    \
        (const __attribute__((address_space(1))) unsigned int*)(g),                      \
        (__attribute__((address_space(3))) unsigned int*)(l), 16, 0, 0)
#else
// host-pass / fallback: synchronous 16B copy (semantically equivalent)
#define GLD16(g, l) (*(bf16x8*)(l) = *(const bf16x8*)(g))
#endif

// ---------------- GEMM core (m97 structure) ----------------
#define GEMM_BODY(A, Bt, K, STORE)                                                       \
    __shared__ __bf16 As[128 * 32];                                                      \
    __shared__ __bf16 Bs[128 * 32];                                                      \
    const int t = threadIdx.x;                                                           \
    const int lane = t & 63;                                                             \
    const int wid = t >> 6;                                                              \
    const int wm = (wid >> 1) << 6;                                                      \
    const int wn = (wid & 1) << 6;                                                       \
    const int bm = blockIdx.x * 128;                                                     \
    const int bn = blockIdx.y * 128;                                                     \
    const int srow = (wid << 4) + (lane >> 2);                                           \
    const int scol = (lane & 3) << 3;                                                    \
    f32x4 acc[4][4];                                                                     \
    _Pragma("unroll") for (int i = 0; i < 4; i++)                                        \
        _Pragma("unroll") for (int j = 0; j < 4; j++)                                    \
            acc[i][j] = (f32x4){0.f, 0.f, 0.f, 0.f};                                     \
    const int m16 = lane & 15;                                                           \
    const int k8 = (lane >> 4) << 3;                                                     \
    for (int k0 = 0; k0 < K; k0 += 32) {                                                 \
        __syncthreads();                                                                 \
        GLD16(A + (size_t)(bm + srow) * K + k0 + scol, As + srow * 32 + scol);           \
        GLD16(A + (size_t)(bm + 64 + srow) * K + k0 + scol, As + (64 + srow) * 32 + scol);\
        GLD16(Bt + (size_t)(bn + srow) * K + k0 + scol, Bs + srow * 32 + scol);          \
        GLD16(Bt + (size_t)(bn + 64 + srow) * K + k0 + scol, Bs + (64 + srow) * 32 + scol);\
        __syncthreads();                                                                 \
        bf16x8 af[4], bfr[4];                                                            \
        _Pragma("unroll") for (int i = 0; i < 4; i++) {                                  \
            af[i] = *(const bf16x8*)(As + (wm + 16 * i + m16) * 32 + k8);                \
            bfr[i] = *(const bf16x8*)(Bs + (wn + 16 * i + m16) * 32 + k8);               \
        }                                                                                \
        _Pragma("unroll") for (int i = 0; i < 4; i++)                                    \
            _Pragma("unroll") for (int j = 0; j < 4; j++)                                \
                acc[i][j] = __builtin_amdgcn_mfma_f32_16x16x32_bf16(af[i], bfr[j],       \
                                                                    acc[i][j], 0, 0, 0); \
    }                                                                                    \
    const int r4 = (lane >> 4) << 2;                                                     \
    STORE

// Single-output: C[M,N] = A @ Bt^T, ldc = N
__global__ __launch_bounds__(256) void gemm_bt(const __bf16* __restrict__ A,
                                               const __bf16* __restrict__ Bt,
                                               __bf16* __restrict__ C,
                                               int M, int N, int K) {
    GEMM_BODY(A, Bt, K,
        _Pragma("unroll") for (int i = 0; i < 4; i++)
            _Pragma("unroll") for (int j = 0; j < 4; j++) {
                int col = bn + wn + 16 * j + m16;
                _Pragma("unroll") for (int r = 0; r < 4; r++) {
                    int row = bm + wm + 16 * i + r4 + r;
                    C[(size_t)row * N + col] = (__bf16)acc[i][j][r];
                }
            })
}

// Dual-output: Bt has 2048 rows; cols 0-1023 -> C0, 1024-2047 -> C1 (both ldc=1024)
__global__ __launch_bounds__(256) void gemm_bt2(const __bf16* __restrict__ A,
                                                const __bf16* __restrict__ Bt,
                                                __bf16* __restrict__ C0,
                                                __bf16* __restrict__ C1,
                                                int M, int K) {
    GEMM_BODY(A, Bt, K,
        __bf16* Cp = (bn < 1024) ? C0 : C1;
        const int cb = bn & 1023;
        _Pragma("unroll") for (int i = 0; i < 4; i++)
            _Pragma("unroll") for (int j = 0; j < 4; j++) {
                int col = cb + wn + 16 * j + m16;
                _Pragma("unroll") for (int r = 0; r < 4; r++) {
                    int row = bm + wm + 16 * i + r4 + r;
                    Cp[(size_t)row * 1024 + col] = (__bf16)acc[i][j][r];
                }
            })
}

// ---------------- combined prep: pack x + all weight transposes, one launch ----------
__device__ __forceinline__ void transpose_tile(const float* __restrict__ W,
                                               __bf16* __restrict__ WT,
                                               int K, int N, int Kp, int Np,
                                               int bx, int by, float* sm) {
    int tx = threadIdx.x & 31, ty = threadIdx.x >> 5;
#pragma unroll
    for (int r = ty; r < 32; r += 8) {
        int k = by * 32 + r, n = bx * 32 + tx;
        float v = 0.f;
        if (k < K && n < N) v = W[(size_t)k * N + n];
        sm[r * 33 + tx] = v;
    }
    __syncthreads();
#pragma unroll
    for (int r = ty; r < 32; r += 8) {
        int n = bx * 32 + r, k = by * 32 + tx;
        if (n < Np && k < Kp) WT[(size_t)n * Kp + k] = (__bf16)sm[tx * 33 + r];
    }
}

__device__ __forceinline__ void transpose_w3_tile(const float* __restrict__ W,
                                                  __bf16* __restrict__ WT,
                                                  int bx, int by, float* sm) {
    int tx = threadIdx.x & 31, ty = threadIdx.x >> 5;
    int r0 = bx * 32;
    int h = r0 >> 7;
    int c0 = r0 & 127;
#pragma unroll
    for (int r = ty; r < 32; r += 8) {
        int k = by * 32 + r;
        int c = c0 + tx;
        float v = 0.f;
        if (c < 121) v = W[(size_t)k * 726 + h * 121 + c];
        sm[r * 33 + tx] = v;
    }
    __syncthreads();
#pragma unroll
    for (int r = ty; r < 32; r += 8) {
        int rr = r0 + r;
        int k = by * 32 + tx;
        WT[(size_t)rr * 1024 + k] = (__bf16)sm[tx * 33 + r];
    }
}

__global__ __launch_bounds__(256) void prep_k(const float* __restrict__ x,
                                              const float* __restrict__ W1,
                                              const float* __restrict__ sW1,
                                              const float* __restrict__ W2,
                                              const float* __restrict__ sW2,
                                              const float* __restrict__ W3,
                                              __bf16* __restrict__ xp,
                                              __bf16* __restrict__ WTcat1,
                                              __bf16* __restrict__ WTcat2,
                                              __bf16* __restrict__ W3pT, int Nn) {
    __shared__ float sm[32 * 33];
    int b = blockIdx.x;
    if (b < 5024) {
        int i = b * 256 + threadIdx.x;
        int n = i >> 6, c = i & 63;
        float v = 0.f;
        if (n < Nn && c < 50) v = x[n * 50 + c];
        xp[(size_t)n * 64 + c] = (__bf16)v;
    } else if (b < 5088) {
        int i = b - 5024; transpose_tile(W1, WTcat1, 50, 1024, 64, 1024, i % 32, i / 32, sm);
    } else if (b < 5152) {
        int i = b - 5088; transpose_tile(sW1, WTcat1 + 1024 * 64, 50, 1024, 64, 1024, i % 32, i / 32, sm);
    } else if (b < 6176) {
        int i = b - 5152; transpose_tile(W2, WTcat2, 1024, 1024, 1024, 1024, i % 32, i / 32, sm);
    } else if (b < 7200) {
        int i = b - 6176; transpose_tile(sW2, WTcat2 + (size_t)1024 * 1024, 1024, 1024, 1024, 1024, i % 32, i / 32, sm);
    } else {
        int i = b - 7200; transpose_w3_tile(W3, W3pT, i % 24, i / 24, sm);
    }
}

// ---------------- CSR build (by dst, self-loops appended, degree padded to x8) ----------
__global__ void zero_probe_k(const int* __restrict__ ei, int* __restrict__ cnt,
                             int* __restrict__ flag, int Nn) {
    int i = blockIdx.x * 256 + threadIdx.x;
    if (i < Nn) cnt[i] = 0;
    if (blockIdx.x == 0 && threadIdx.x == 0) {
        int all0 = 1;
        for (int k = 0; k < 64; k++)
            if (ei[2 * k + 1] != 0) { all0 = 0; break; }
        *flag = all0;
    }
}

__device__ __forceinline__ int load_ei(const int* ei, int idx, int is64) {
    return is64 ? ei[2 * idx] : ei[idx];
}

__global__ void hist_k(const int* __restrict__ ei, const int* __restrict__ flag,
                       int* __restrict__ cnt, int E, int Nn) {
    int e = blockIdx.x * 256 + threadIdx.x;
    if (e >= E + Nn) return;
    int is64 = *flag;
    int d = (e < E) ? load_ei(ei, E + e, is64) : (e - E);
    d = min(max(d, 0), Nn - 1);
    atomicAdd(&cnt[d], 1);
}

// exclusive scan over x8-PADDED counts; zeros cnt afterwards (cursor for fill)
__global__ __launch_bounds__(1024) void scan_k(int* __restrict__ cnt, int* __restrict__ row_ptr,
                                               int Nn) {
    __shared__ int part[1024];
    int t = threadIdx.x;
    int chunk = (Nn + 1023) >> 10;
    int lo = t * chunk;
    int hi = lo + chunk; if (hi > Nn) hi = Nn; if (lo > Nn) lo = Nn;
    int s = 0;
    for (int i = lo; i < hi; i++) s += (cnt[i] + 7) & ~7;
    part[t] = s;
    __syncthreads();
    for (int off = 1; off < 1024; off <<= 1) {
        int v = (t >= off) ? part[t - off] : 0;
        __syncthreads();
        part[t] += v;
        __syncthreads();
    }
    int run = part[t] - s;
    for (int i = lo; i < hi; i++) { row_ptr[i] = run; run += (cnt[i] + 7) & ~7; }
    if (t == 1023) row_ptr[Nn] = part[1023];
    __syncthreads();
    for (int i = lo; i < hi; i++) cnt[i] = 0;
}

__global__ void fill_csr_k(const int* __restrict__ ei, const int* __restrict__ flag,
                           const int* __restrict__ row_ptr, int* __restrict__ cursor,
                           int* __restrict__ src_csr, int E, int Nn) {
    int e = blockIdx.x * 256 + threadIdx.x;
    if (e >= E + Nn) return;
    int is64 = *flag;
    int d = (e < E) ? load_ei(ei, E + e, is64) : (e - E);
    int s = (e < E) ? load_ei(ei, e, is64) : (e - E);
    d = min(max(d, 0), Nn - 1);
    s = min(max(s, 0), Nn - 1);
    int slot = row_ptr[d] + atomicAdd(&cursor[d], 1);
    src_csr[slot] = s;
}

// ---------------- per-(node,head) attention dots ----------------
__global__ void alpha_k(const __bf16* __restrict__ XL, int ld, const float* __restrict__ a_src,
                        const float* __restrict__ a_dst, float* __restrict__ asrc,
                        float* __restrict__ adst, int Nn, int H, int C, int Cpad) {
    int gw = (blockIdx.x * 256 + threadIdx.x) >> 6;
    int lane = threadIdx.x & 63;
    if (gw >= Nn * H) return;
    int n = gw / H, h = gw - n * H;
    const __bf16* row = XL + (size_t)n * ld + h * Cpad;
    const float* as = a_src + h * C;
    const float* ad = a_dst + h * C;
    float s = 0.f, d = 0.f;
    for (int c = lane; c < C; c += 64) {
        float v = (float)row[c];
        s += v * as[c];
        d += v * ad[c];
    }
#pragma unroll
    for (int off = 32; off; off >>= 1) {
        s += __shfl_down(s, off);
        d += __shfl_down(d, off);
    }
    if (lane == 0) { asrc[n * H + h] = s; adst[n * H + h] = d; }
}

// ------- per-node segment softmax -> transposed edge weights wt[h][Ecap] ----------
__global__ void attn_k(const int* __restrict__ row_ptr, const int* __restrict__ deg,
                       const int* __restrict__ src_csr,
                       const float* __restrict__ asrc, const float* __restrict__ adst,
                       float* __restrict__ wt, int Nn, int H, int Ecap) {
    int gw = (blockIdx.x * 256 + threadIdx.x) >> 6;
    int lane = threadIdx.x & 63;
    if (gw >= Nn) return;
    int n = gw;
    int base = row_ptr[n], dg = deg[n];
    if (dg <= 64) {
        // fast path: one edge per lane, single pass
        bool v = lane < dg;
        int src = v ? src_csr[base + lane] : 0;
        for (int h = 0; h < H; h++) {
            float ad = adst[n * H + h];
            float e = -1e30f;
            if (v) {
                e = asrc[src * H + h] + ad;
                e = e > 0.f ? e : 0.2f * e;
            }
            float m = e;
#pragma unroll
            for (int off = 1; off < 64; off <<= 1) m = fmaxf(m, __shfl_xor(m, off));
            float ex = v ? __expf(e - m) : 0.f;
            float sum = ex;
#pragma unroll
            for (int off = 1; off < 64; off <<= 1) sum += __shfl_xor(sum, off);
            if (v) wt[(size_t)h * Ecap + base + lane] = ex / (sum + 1e-16f);
        }
        return;
    }
    for (int h = 0; h < H; h++) {
        float ad = adst[n * H + h];
        float m = -1e30f;
        for (int s = lane; s < dg; s += 64) {
            float e = asrc[src_csr[base + s] * H + h] + ad;
            e = e > 0.f ? e : 0.2f * e;
            m = fmaxf(m, e);
        }
#pragma unroll
        for (int off = 1; off < 64; off <<= 1) m = fmaxf(m, __shfl_xor(m, off));
        float sum = 0.f;
        for (int s = lane; s < dg; s += 64) {
            float e = asrc[src_csr[base + s] * H + h] + ad;
            e = e > 0.f ? e : 0.2f * e;
            sum += __expf(e - m);
        }
#pragma unroll
        for (int off = 1; off < 64; off <<= 1) sum += __shfl_xor(sum, off);
        float inv = 1.f / (sum + 1e-16f);
        float* wrow = wt + (size_t)h * Ecap;
        for (int s = lane; s < dg; s += 64) {
            float e = asrc[src_csr[base + s] * H + h] + ad;
            e = e > 0.f ? e : 0.2f * e;
            wrow[base + s] = __expf(e - m) * inv;
        }
    }
}

// ------- XCD-sharded aggregation, layers 1/2 (H=4, C=256, ld=1024), x8-padded CSR -------
__global__ __launch_bounds__(256) void agg_skip8(const __bf16* __restrict__ XL,
                                                 const float* __restrict__ wt,
                                                 const int* __restrict__ row_ptr,
                                                 const int* __restrict__ src_csr,
                                                 const float* __restrict__ bias,
                                                 const float* __restrict__ sb,
                                                 __bf16* __restrict__ SK, int Nn, int Ecap) {
    const int cc = blockIdx.x;                 // 0..7
    const int n = blockIdx.y * 4 + (threadIdx.x >> 6);
    const int lane = threadIdx.x & 63;
    if (n >= Nn) return;
    const int g = lane >> 4;                   // edge group 0..3, 2 contiguous edges each
    const int p = lane & 15;
    const int col = cc * 128 + p * 8;
    const float* wrow = wt + (size_t)(cc >> 1) * Ecap;
    const __bf16* XLc = XL + col;
    const int base = row_ptr[n], end = row_ptr[n + 1];

    float acc[8];
#pragma unroll
    for (int j = 0; j < 8; j++) acc[j] = 0.f;

    for (int e = base; e < end; e += 8) {
        int2 si = *(const int2*)(src_csr + e + 2 * g);
        float2 wv = *(const float2*)(wrow + e + 2 * g);
        bf16x8 xa = *(const bf16x8*)(XLc + (size_t)si.x * 1024);
        bf16x8 xb = *(const bf16x8*)(XLc + (size_t)si.y * 1024);
#pragma unroll
        for (int j = 0; j < 8; j++) acc[j] += wv.x * (float)xa[j] + wv.y * (float)xb[j];
    }
#pragma unroll
    for (int j = 0; j < 8; j++) {
        acc[j] += __shfl_xor(acc[j], 16);
        acc[j] += __shfl_xor(acc[j], 32);
    }
    if (lane < 16) {
        size_t o = (size_t)n * 1024 + col;
        bf16x8 sk = *(const bf16x8*)(SK + o);
        bf16x8 res;
#pragma unroll
        for (int j = 0; j < 8; j++)
            res[j] = (__bf16)(acc[j] + bias[col + j] + sb[col + j] + (float)sk[j]);
        *(bf16x8*)(SK + o) = res;
    }
}

// ------- layer-3 aggregation, head-aligned xl [n][6*128] -> bf16 partials [n][768] ------
__global__ __launch_bounds__(256) void agg_mean8(const __bf16* __restrict__ XL,
                                                 const float* __restrict__ wt,
                                                 const int* __restrict__ row_ptr,
                                                 const int* __restrict__ src_csr,
                                                 __bf16* __restrict__ part, int Nn, int Ecap) {
    const int cc = blockIdx.x;                 // head 0..5
    const int n = blockIdx.y * 4 + (threadIdx.x >> 6);
    const int lane = threadIdx.x & 63;
    if (n >= Nn) return;
    const int g = lane >> 4;
    const int p = lane & 15;
    const int col = cc * 128 + p * 8;
    const float* wrow = wt + (size_t)cc * Ecap;
    const __bf16* XLc = XL + col;
    const int base = row_ptr[n], end = row_ptr[n + 1];

    float acc[8];
#pragma unroll
    for (int j = 0; j < 8; j++) acc[j] = 0.f;

    for (int e = base; e < end; e += 8) {
        int2 si = *(const int2*)(src_csr + e + 2 * g);
        float2 wv = *(const float2*)(wrow + e + 2 * g);
        bf16x8 xa = *(const bf16x8*)(XLc + (size_t)si.x * 768);
        bf16x8 xb = *(const bf16x8*)(XLc + (size_t)si.y * 768);
#pragma unroll
        for (int j = 0; j < 8; j++) acc[j] += wv.x * (float)xa[j] + wv.y * (float)xb[j];
    }
#pragma unroll
    for (int j = 0; j < 8; j++) {
        acc[j] += __shfl_xor(acc[j], 16);
        acc[j] += __shfl_xor(acc[j], 32);
    }
    if (lane < 16) {
        size_t o = (size_t)n * 768 + col;
        bf16x8 res;
#pragma unroll
        for (int j = 0; j < 8; j++) res[j] = (__bf16)acc[j];
        *(bf16x8*)(part + o) = res;
    }
}

// -------- head-mean over bf16 partials (head stride 128) + bias -> fp32 out --------
__global__ __launch_bounds__(128) void reduce_mean_k(const __bf16* __restrict__ part,
                                                     const float* __restrict__ b3,
                                                     float* __restrict__ out, int Nn) {
    int n = blockIdx.x;
    int t = threadIdx.x;
    if (t >= 121) return;
    const __bf16* row = part + (size_t)n * 768;
    float s = 0.f;
#pragma unroll
    for (int h = 0; h < 6; h++) s += (float)row[h * 128 + t];
    out[(size_t)n * 121 + t] = s * (1.f / 6.f) + b3[t];
}

// ---------------- LayerNorm + ELU ----------------
__global__ __launch_bounds__(256) void ln_elu_k(const __bf16* __restrict__ in,
                                                const float* __restrict__ g,
                                                const float* __restrict__ be,
                                                __bf16* __restrict__ out, int rows_real) {
    const int D = 1024;
    int n = blockIdx.x;
    int t = threadIdx.x;
    size_t ro = (size_t)n * D;
    if (n >= rows_real) {
#pragma unroll
        for (int j = 0; j < 4; j++) out[ro + t + 256 * j] = (__bf16)0.f;
        return;
    }
    float v[4];
    float s = 0.f, q = 0.f;
#pragma unroll
    for (int j = 0; j < 4; j++) {
        int c = t + 256 * j;
        float a = (float)in[ro + c];
        v[j] = a;
        s += a;
        q += a * a;
    }
#pragma unroll
    for (int off = 32; off; off >>= 1) {
        s += __shfl_down(s, off);
        q += __shfl_down(q, off);
    }
    __shared__ float rs[8];
    int wid = t >> 6;
    if ((t & 63) == 0) { rs[wid] = s; rs[wid + 4] = q; }
    __syncthreads();
    s = rs[0] + rs[1] + rs[2] + rs[3];
    q = rs[4] + rs[5] + rs[6] + rs[7];
    float mu = s * (1.f / 1024.f);
    float var = q * (1.f / 1024.f) - mu * mu;
    float inv = rsqrtf(fmaxf(var, 0.f) + 1e-5f);
#pragma unroll
    for (int j = 0; j < 4; j++) {
        int c = t + 256 * j;
        float y = (v[j] - mu) * inv * g[c] + be[c];
        y = y > 0.f ? y : expm1f(y);
        out[ro + c] = (__bf16)y;
    }
}

extern "C" void kernel_launch(void* const* d_in, const int* in_sizes, int n_in,
                              void* d_out, int out_size, void* d_ws, size_t ws_size,
                              hipStream_t stream) {
    const float* x   = (const float*)d_in[0];
    const int*   ei  = (const int*)d_in[1];
    const float* W1  = (const float*)d_in[2];
    const float* as1 = (const float*)d_in[3];
    const float* ad1 = (const float*)d_in[4];
    const float* b1  = (const float*)d_in[5];
    const float* W2  = (const float*)d_in[6];
    const float* as2 = (const float*)d_in[7];
    const float* ad2 = (const float*)d_in[8];
    const float* b2  = (const float*)d_in[9];
    const float* W3  = (const float*)d_in[10];
    const float* as3 = (const float*)d_in[11];
    const float* ad3 = (const float*)d_in[12];
    const float* b3  = (const float*)d_in[13];
    const float* sW1 = (const float*)d_in[14];
    const float* sb1 = (const float*)d_in[15];
    const float* sW2 = (const float*)d_in[16];
    const float* sb2 = (const float*)d_in[17];
    const float* g1  = (const float*)d_in[18];
    const float* be1 = (const float*)d_in[19];
    const float* g2  = (const float*)d_in[20];
    const float* be2 = (const float*)d_in[21];
    float* out = (float*)d_out;

    const int Nn = 20000;
    const int E = in_sizes[1] / 2;         // 320000
    const int E2 = E + Nn;                 // 340000
    const int Ecap = E2 + 8 * Nn;          // x8-padded CSR capacity (500000)
    const int Mpad = 20096;                // 157*128

    char* p = (char*)d_ws;
    auto alloc = [&](size_t bytes) {
        char* r = p;
        p += (bytes + 255) & ~(size_t)255;
        return r;
    };
    __bf16* WTcat1 = (__bf16*)alloc((size_t)2048 * 64 * 2);
    __bf16* WTcat2 = (__bf16*)alloc((size_t)2048 * 1024 * 2);
    __bf16* W3pT   = (__bf16*)alloc((size_t)768 * 1024 * 2);
    __bf16* xp     = (__bf16*)alloc((size_t)Mpad * 64 * 2);
    __bf16* XL     = (__bf16*)alloc((size_t)Mpad * 1024 * 2);
    __bf16* SK     = (__bf16*)alloc((size_t)Mpad * 1024 * 2);
    __bf16* H1     = (__bf16*)alloc((size_t)Mpad * 1024 * 2);
    float*  asrcb  = (float*)alloc((size_t)Nn * 6 * 4);
    float*  adstb  = (float*)alloc((size_t)Nn * 6 * 4);
    float*  wbuf   = (float*)alloc((size_t)6 * Ecap * 4);
    int*    rowp   = (int*)alloc((size_t)(Nn + 1) * 4);
    int*    cnt    = (int*)alloc((size_t)Nn * 4);
    int*    scsr   = (int*)alloc((size_t)Ecap * 4);
    int*    eiflag = (int*)alloc(256);
    __bf16* part   = SK;   // SK dead by layer 3
    (void)ws_size; (void)n_in; (void)out_size;

    // ---- prep (1 launch) ----
    prep_k<<<7968, 256, 0, stream>>>(x, W1, sW1, W2, sW2, W3, xp, WTcat1, WTcat2, W3pT, Nn);

    // ---- padded CSR ----
    zero_probe_k<<<(Nn + 255) / 256, 256, 0, stream>>>(ei, cnt, eiflag, Nn);
    hist_k<<<(E2 + 255) / 256, 256, 0, stream>>>(ei, eiflag, cnt, E, Nn);
    scan_k<<<1, 1024, 0, stream>>>(cnt, rowp, Nn);
    (void)hipMemsetAsync(scsr, 0, (size_t)Ecap * 4, stream);          // dummy src = 0
    (void)hipMemsetAsync(wbuf, 0, (size_t)6 * Ecap * 4, stream);      // dummy w = 0
    fill_csr_k<<<(E2 + 255) / 256, 256, 0, stream>>>(ei, eiflag, rowp, cnt, scsr, E, Nn);
    // cnt now holds real degrees

    // ---- layer 1: 50 -> 4x256 concat ----
    gemm_bt2<<<dim3(Mpad / 128, 16), 256, 0, stream>>>(xp, WTcat1, XL, SK, Mpad, 64);
    alpha_k<<<(Nn * 4 * 64) / 256, 256, 0, stream>>>(XL, 1024, as1, ad1, asrcb, adstb, Nn, 4, 256, 256);
    attn_k<<<(Nn + 3) / 4, 256, 0, stream>>>(rowp, cnt, scsr, asrcb, adstb, wbuf, Nn, 4, Ecap);
    agg_skip8<<<dim3(8, (Nn + 3) / 4), 256, 0, stream>>>(XL, wbuf, rowp, scsr, b1, sb1, SK, Nn, Ecap);
    ln_elu_k<<<Mpad, 256, 0, stream>>>(SK, g1, be1, H1, Nn);

    // ---- layer 2: 1024 -> 4x256 concat ----
    gemm_bt2<<<dim3(Mpad / 128, 16), 256, 0, stream>>>(H1, WTcat2, XL, SK, Mpad, 1024);
    alpha_k<<<(Nn * 4 * 64) / 256, 256, 0, stream>>>(XL, 1024, as2, ad2, asrcb, adstb, Nn, 4, 256, 256);
    attn_k<<<(Nn + 3) / 4, 256, 0, stream>>>(rowp, cnt, scsr, asrcb, adstb, wbuf, Nn, 4, Ecap);
    agg_skip8<<<dim3(8, (Nn + 3) / 4), 256, 0, stream>>>(XL, wbuf, rowp, scsr, b2, sb2, SK, Nn, Ecap);
    ln_elu_k<<<Mpad, 256, 0, stream>>>(SK, g2, be2, H1, Nn);  // H1 := h2

    // ---- layer 3: 1024 -> 6x(121 pad 128), mean over heads ----
    gemm_bt<<<dim3(Mpad / 128, 6), 256, 0, stream>>>(H1, W3pT, XL, Mpad, 768, 1024);
    alpha_k<<<(Nn * 6 * 64) / 256, 256, 0, stream>>>(XL, 768, as3, ad3, asrcb, adstb, Nn, 6, 121, 128);
    attn_k<<<(Nn + 3) / 4, 256, 0, stream>>>(rowp, cnt, scsr, asrcb, adstb, wbuf, Nn, 6, Ecap);
    agg_mean8<<<dim3(6, (Nn + 3) / 4), 256, 0, stream>>>(XL, wbuf, rowp, scsr, part, Nn, Ecap);
    reduce_mean_k<<<Nn, 128, 0, stream>>>(part, b3, out, Nn);
}

// Round 10
// 780.246 us; speedup vs baseline: 1.4065x; 1.0221x over previous
//
#include <hip/hip_runtime.h>
#include <hip/hip_bf16.h>
#include <math.h>

typedef __attribute__((ext_vector_type(8))) __bf16 bf16x8;
typedef __attribute__((ext_vector_type(4))) float f32x4;

#if __has_builtin(__builtin_amdgcn_global_load_lds)
#define GLD16(g, l)                                                                      \
    __builtin_amdgcn_global_load_lds(                                                    \
        (const __attribute__((address_space(1))) unsigned int*)(g),                      \
        (__attribute__((address_space(3))) unsigned int*)(l), 16, 0, 0)
#else
// host-pass / fallback: synchronous 16B copy (semantically equivalent)
#define GLD16(g, l) (*(bf16x8*)(l) = *(const bf16x8*)(g))
#endif

// ---------------- GEMM core (m97 structure) ----------------
// Grid: blockIdx.x = column tile (few), blockIdx.y = row tile (many) so the resident
// block cohort shares one A-tile and B stays L2-hot per XCD (fixes 8x A over-fetch).
#define GEMM_BODY(A, Bt, K, STORE)                                                       \
    __shared__ __bf16 As[128 * 32];                                                      \
    __shared__ __bf16 Bs[128 * 32];                                                      \
    const int t = threadIdx.x;                                                           \
    const int lane = t & 63;                                                             \
    const int wid = t >> 6;                                                              \
    const int wm = (wid >> 1) << 6;                                                      \
    const int wn = (wid & 1) << 6;                                                       \
    const int bm = blockIdx.y * 128;                                                     \
    const int bn = blockIdx.x * 128;                                                     \
    const int srow = (wid << 4) + (lane >> 2);                                           \
    const int scol = (lane & 3) << 3;                                                    \
    f32x4 acc[4][4];                                                                     \
    _Pragma("unroll") for (int i = 0; i < 4; i++)                                        \
        _Pragma("unroll") for (int j = 0; j < 4; j++)                                    \
            acc[i][j] = (f32x4){0.f, 0.f, 0.f, 0.f};                                     \
    const int m16 = lane & 15;                                                           \
    const int k8 = (lane >> 4) << 3;                                                     \
    for (int k0 = 0; k0 < K; k0 += 32) {                                                 \
        __syncthreads();                                                                 \
        GLD16(A + (size_t)(bm + srow) * K + k0 + scol, As + srow * 32 + scol);           \
        GLD16(A + (size_t)(bm + 64 + srow) * K + k0 + scol, As + (64 + srow) * 32 + scol);\
        GLD16(Bt + (size_t)(bn + srow) * K + k0 + scol, Bs + srow * 32 + scol);          \
        GLD16(Bt + (size_t)(bn + 64 + srow) * K + k0 + scol, Bs + (64 + srow) * 32 + scol);\
        __syncthreads();                                                                 \
        bf16x8 af[4], bfr[4];                                                            \
        _Pragma("unroll") for (int i = 0; i < 4; i++) {                                  \
            af[i] = *(const bf16x8*)(As + (wm + 16 * i + m16) * 32 + k8);                \
            bfr[i] = *(const bf16x8*)(Bs + (wn + 16 * i + m16) * 32 + k8);               \
        }                                                                                \
        _Pragma("unroll") for (int i = 0; i < 4; i++)                                    \
            _Pragma("unroll") for (int j = 0; j < 4; j++)                                \
                acc[i][j] = __builtin_amdgcn_mfma_f32_16x16x32_bf16(af[i], bfr[j],       \
                                                                    acc[i][j], 0, 0, 0); \
    }                                                                                    \
    const int r4 = (lane >> 4) << 2;                                                     \
    STORE

// Single-output: C[M,N] = A @ Bt^T, ldc = N
__global__ __launch_bounds__(256) void gemm_bt(const __bf16* __restrict__ A,
                                               const __bf16* __restrict__ Bt,
                                               __bf16* __restrict__ C,
                                               int M, int N, int K) {
    GEMM_BODY(A, Bt, K,
        _Pragma("unroll") for (int i = 0; i < 4; i++)
            _Pragma("unroll") for (int j = 0; j < 4; j++) {
                int col = bn + wn + 16 * j + m16;
                _Pragma("unroll") for (int r = 0; r < 4; r++) {
                    int row = bm + wm + 16 * i + r4 + r;
                    C[(size_t)row * N + col] = (__bf16)acc[i][j][r];
                }
            })
}

// Dual-output: Bt has 2048 rows; cols 0-1023 -> C0, 1024-2047 -> C1 (both ldc=1024)
__global__ __launch_bounds__(256) void gemm_bt2(const __bf16* __restrict__ A,
                                                const __bf16* __restrict__ Bt,
                                                __bf16* __restrict__ C0,
                                                __bf16* __restrict__ C1,
                                                int M, int K) {
    GEMM_BODY(A, Bt, K,
        __bf16* Cp = (bn < 1024) ? C0 : C1;
        const int cb = bn & 1023;
        _Pragma("unroll") for (int i = 0; i < 4; i++)
            _Pragma("unroll") for (int j = 0; j < 4; j++) {
                int col = cb + wn + 16 * j + m16;
                _Pragma("unroll") for (int r = 0; r < 4; r++) {
                    int row = bm + wm + 16 * i + r4 + r;
                    Cp[(size_t)row * 1024 + col] = (__bf16)acc[i][j][r];
                }
            })
}

// ---------------- combined prep: pack x + all weight transposes, one launch ----------
__device__ __forceinline__ void transpose_tile(const float* __restrict__ W,
                                               __bf16* __restrict__ WT,
                                               int K, int N, int Kp, int Np,
                                               int bx, int by, float* sm) {
    int tx = threadIdx.x & 31, ty = threadIdx.x >> 5;
#pragma unroll
    for (int r = ty; r < 32; r += 8) {
        int k = by * 32 + r, n = bx * 32 + tx;
        float v = 0.f;
        if (k < K && n < N) v = W[(size_t)k * N + n];
        sm[r * 33 + tx] = v;
    }
    __syncthreads();
#pragma unroll
    for (int r = ty; r < 32; r += 8) {
        int n = bx * 32 + r, k = by * 32 + tx;
        if (n < Np && k < Kp) WT[(size_t)n * Kp + k] = (__bf16)sm[tx * 33 + r];
    }
}

__device__ __forceinline__ void transpose_w3_tile(const float* __restrict__ W,
                                                  __bf16* __restrict__ WT,
                                                  int bx, int by, float* sm) {
    int tx = threadIdx.x & 31, ty = threadIdx.x >> 5;
    int r0 = bx * 32;
    int h = r0 >> 7;
    int c0 = r0 & 127;
#pragma unroll
    for (int r = ty; r < 32; r += 8) {
        int k = by * 32 + r;
        int c = c0 + tx;
        float v = 0.f;
        if (c < 121) v = W[(size_t)k * 726 + h * 121 + c];
        sm[r * 33 + tx] = v;
    }
    __syncthreads();
#pragma unroll
    for (int r = ty; r < 32; r += 8) {
        int rr = r0 + r;
        int k = by * 32 + tx;
        WT[(size_t)rr * 1024 + k] = (__bf16)sm[tx * 33 + r];
    }
}

__global__ __launch_bounds__(256) void prep_k(const float* __restrict__ x,
                                              const float* __restrict__ W1,
                                              const float* __restrict__ sW1,
                                              const float* __restrict__ W2,
                                              const float* __restrict__ sW2,
                                              const float* __restrict__ W3,
                                              __bf16* __restrict__ xp,
                                              __bf16* __restrict__ WTcat1,
                                              __bf16* __restrict__ WTcat2,
                                              __bf16* __restrict__ W3pT, int Nn) {
    __shared__ float sm[32 * 33];
    int b = blockIdx.x;
    if (b < 5024) {
        int i = b * 256 + threadIdx.x;
        int n = i >> 6, c = i & 63;
        float v = 0.f;
        if (n < Nn && c < 50) v = x[n * 50 + c];
        xp[(size_t)n * 64 + c] = (__bf16)v;
    } else if (b < 5088) {
        int i = b - 5024; transpose_tile(W1, WTcat1, 50, 1024, 64, 1024, i % 32, i / 32, sm);
    } else if (b < 5152) {
        int i = b - 5088; transpose_tile(sW1, WTcat1 + 1024 * 64, 50, 1024, 64, 1024, i % 32, i / 32, sm);
    } else if (b < 6176) {
        int i = b - 5152; transpose_tile(W2, WTcat2, 1024, 1024, 1024, 1024, i % 32, i / 32, sm);
    } else if (b < 7200) {
        int i = b - 6176; transpose_tile(sW2, WTcat2 + (size_t)1024 * 1024, 1024, 1024, 1024, 1024, i % 32, i / 32, sm);
    } else {
        int i = b - 7200; transpose_w3_tile(W3, W3pT, i % 24, i / 24, sm);
    }
}

// ---------------- CSR build (by dst, self-loops appended, degree padded to x8) ----------
__global__ void zero_probe_k(const int* __restrict__ ei, int* __restrict__ cnt,
                             int* __restrict__ flag, int Nn) {
    int i = blockIdx.x * 256 + threadIdx.x;
    if (i < Nn) cnt[i] = 0;
    if (blockIdx.x == 0 && threadIdx.x == 0) {
        int all0 = 1;
        for (int k = 0; k < 64; k++)
            if (ei[2 * k + 1] != 0) { all0 = 0; break; }
        *flag = all0;
    }
}

__device__ __forceinline__ int load_ei(const int* ei, int idx, int is64) {
    return is64 ? ei[2 * idx] : ei[idx];
}

__global__ void hist_k(const int* __restrict__ ei, const int* __restrict__ flag,
                       int* __restrict__ cnt, int E, int Nn) {
    int e = blockIdx.x * 256 + threadIdx.x;
    if (e >= E + Nn) return;
    int is64 = *flag;
    int d = (e < E) ? load_ei(ei, E + e, is64) : (e - E);
    d = min(max(d, 0), Nn - 1);
    atomicAdd(&cnt[d], 1);
}

// exclusive scan over x8-PADDED counts; zeros cnt afterwards (cursor for fill)
__global__ __launch_bounds__(1024) void scan_k(int* __restrict__ cnt, int* __restrict__ row_ptr,
                                               int Nn) {
    __shared__ int part[1024];
    int t = threadIdx.x;
    int chunk = (Nn + 1023) >> 10;
    int lo = t * chunk;
    int hi = lo + chunk; if (hi > Nn) hi = Nn; if (lo > Nn) lo = Nn;
    int s = 0;
    for (int i = lo; i < hi; i++) s += (cnt[i] + 7) & ~7;
    part[t] = s;
    __syncthreads();
    for (int off = 1; off < 1024; off <<= 1) {
        int v = (t >= off) ? part[t - off] : 0;
        __syncthreads();
        part[t] += v;
        __syncthreads();
    }
    int run = part[t] - s;
    for (int i = lo; i < hi; i++) { row_ptr[i] = run; run += (cnt[i] + 7) & ~7; }
    if (t == 1023) row_ptr[Nn] = part[1023];
    __syncthreads();
    for (int i = lo; i < hi; i++) cnt[i] = 0;
}

__global__ void fill_csr_k(const int* __restrict__ ei, const int* __restrict__ flag,
                           const int* __restrict__ row_ptr, int* __restrict__ cursor,
                           int* __restrict__ src_csr, int E, int Nn) {
    int e = blockIdx.x * 256 + threadIdx.x;
    if (e >= E + Nn) return;
    int is64 = *flag;
    int d = (e < E) ? load_ei(ei, E + e, is64) : (e - E);
    int s = (e < E) ? load_ei(ei, e, is64) : (e - E);
    d = min(max(d, 0), Nn - 1);
    s = min(max(s, 0), Nn - 1);
    int slot = row_ptr[d] + atomicAdd(&cursor[d], 1);
    src_csr[slot] = s;
}

// ---------------- per-(node,head) attention dots ----------------
__global__ void alpha_k(const __bf16* __restrict__ XL, int ld, const float* __restrict__ a_src,
                        const float* __restrict__ a_dst, float* __restrict__ asrc,
                        float* __restrict__ adst, int Nn, int H, int C, int Cpad) {
    int gw = (blockIdx.x * 256 + threadIdx.x) >> 6;
    int lane = threadIdx.x & 63;
    if (gw >= Nn * H) return;
    int n = gw / H, h = gw - n * H;
    const __bf16* row = XL + (size_t)n * ld + h * Cpad;
    const float* as = a_src + h * C;
    const float* ad = a_dst + h * C;
    float s = 0.f, d = 0.f;
    for (int c = lane; c < C; c += 64) {
        float v = (float)row[c];
        s += v * as[c];
        d += v * ad[c];
    }
#pragma unroll
    for (int off = 32; off; off >>= 1) {
        s += __shfl_down(s, off);
        d += __shfl_down(d, off);
    }
    if (lane == 0) { asrc[n * H + h] = s; adst[n * H + h] = d; }
}

// ------- per-node segment softmax -> transposed edge weights wt[h][Ecap] ----------
__global__ void attn_k(const int* __restrict__ row_ptr, const int* __restrict__ deg,
                       const int* __restrict__ src_csr,
                       const float* __restrict__ asrc, const float* __restrict__ adst,
                       float* __restrict__ wt, int Nn, int H, int Ecap) {
    int gw = (blockIdx.x * 256 + threadIdx.x) >> 6;
    int lane = threadIdx.x & 63;
    if (gw >= Nn) return;
    int n = gw;
    int base = row_ptr[n], dg = deg[n];
    if (dg <= 64) {
        // fast path: one edge per lane, single pass
        bool v = lane < dg;
        int src = v ? src_csr[base + lane] : 0;
        for (int h = 0; h < H; h++) {
            float ad = adst[n * H + h];
            float e = -1e30f;
            if (v) {
                e = asrc[src * H + h] + ad;
                e = e > 0.f ? e : 0.2f * e;
            }
            float m = e;
#pragma unroll
            for (int off = 1; off < 64; off <<= 1) m = fmaxf(m, __shfl_xor(m, off));
            float ex = v ? __expf(e - m) : 0.f;
            float sum = ex;
#pragma unroll
            for (int off = 1; off < 64; off <<= 1) sum += __shfl_xor(sum, off);
            if (v) wt[(size_t)h * Ecap + base + lane] = ex / (sum + 1e-16f);
        }
        return;
    }
    for (int h = 0; h < H; h++) {
        float ad = adst[n * H + h];
        float m = -1e30f;
        for (int s = lane; s < dg; s += 64) {
            float e = asrc[src_csr[base + s] * H + h] + ad;
            e = e > 0.f ? e : 0.2f * e;
            m = fmaxf(m, e);
        }
#pragma unroll
        for (int off = 1; off < 64; off <<= 1) m = fmaxf(m, __shfl_xor(m, off));
        float sum = 0.f;
        for (int s = lane; s < dg; s += 64) {
            float e = asrc[src_csr[base + s] * H + h] + ad;
            e = e > 0.f ? e : 0.2f * e;
            sum += __expf(e - m);
        }
#pragma unroll
        for (int off = 1; off < 64; off <<= 1) sum += __shfl_xor(sum, off);
        float inv = 1.f / (sum + 1e-16f);
        float* wrow = wt + (size_t)h * Ecap;
        for (int s = lane; s < dg; s += 64) {
            float e = asrc[src_csr[base + s] * H + h] + ad;
            e = e > 0.f ? e : 0.2f * e;
            wrow[base + s] = __expf(e - m) * inv;
        }
    }
}

// ------- XCD-sharded aggregation, layers 1/2 (H=4, C=256, ld=1024), x8-padded CSR -------
__global__ __launch_bounds__(256) void agg_skip8(const __bf16* __restrict__ XL,
                                                 const float* __restrict__ wt,
                                                 const int* __restrict__ row_ptr,
                                                 const int* __restrict__ src_csr,
                                                 const float* __restrict__ bias,
                                                 const float* __restrict__ sb,
                                                 __bf16* __restrict__ SK, int Nn, int Ecap) {
    const int cc = blockIdx.x;                 // 0..7
    const int n = blockIdx.y * 4 + (threadIdx.x >> 6);
    const int lane = threadIdx.x & 63;
    if (n >= Nn) return;
    const int g = lane >> 4;                   // edge group 0..3, 2 contiguous edges each
    const int p = lane & 15;
    const int col = cc * 128 + p * 8;
    const float* wrow = wt + (size_t)(cc >> 1) * Ecap;
    const __bf16* XLc = XL + col;
    const int base = row_ptr[n], end = row_ptr[n + 1];

    float acc[8];
#pragma unroll
    for (int j = 0; j < 8; j++) acc[j] = 0.f;

    for (int e = base; e < end; e += 8) {
        int2 si = *(const int2*)(src_csr + e + 2 * g);
        float2 wv = *(const float2*)(wrow + e + 2 * g);
        bf16x8 xa = *(const bf16x8*)(XLc + (size_t)si.x * 1024);
        bf16x8 xb = *(const bf16x8*)(XLc + (size_t)si.y * 1024);
#pragma unroll
        for (int j = 0; j < 8; j++) acc[j] += wv.x * (float)xa[j] + wv.y * (float)xb[j];
    }
#pragma unroll
    for (int j = 0; j < 8; j++) {
        acc[j] += __shfl_xor(acc[j], 16);
        acc[j] += __shfl_xor(acc[j], 32);
    }
    if (lane < 16) {
        size_t o = (size_t)n * 1024 + col;
        bf16x8 sk = *(const bf16x8*)(SK + o);
        bf16x8 res;
#pragma unroll
        for (int j = 0; j < 8; j++)
            res[j] = (__bf16)(acc[j] + bias[col + j] + sb[col + j] + (float)sk[j]);
        *(bf16x8*)(SK + o) = res;
    }
}

// ------- layer-3 aggregation, head-aligned xl [n][6*128] -> bf16 partials [n][768] ------
__global__ __launch_bounds__(256) void agg_mean8(const __bf16* __restrict__ XL,
                                                 const float* __restrict__ wt,
                                                 const int* __restrict__ row_ptr,
                                                 const int* __restrict__ src_csr,
                                                 __bf16* __restrict__ part, int Nn, int Ecap) {
    const int cc = blockIdx.x;                 // head 0..5
    const int n = blockIdx.y * 4 + (threadIdx.x >> 6);
    const int lane = threadIdx.x & 63;
    if (n >= Nn) return;
    const int g = lane >> 4;
    const int p = lane & 15;
    const int col = cc * 128 + p * 8;
    const float* wrow = wt + (size_t)cc * Ecap;
    const __bf16* XLc = XL + col;
    const int base = row_ptr[n], end = row_ptr[n + 1];

    float acc[8];
#pragma unroll
    for (int j = 0; j < 8; j++) acc[j] = 0.f;

    for (int e = base; e < end; e += 8) {
        int2 si = *(const int2*)(src_csr + e + 2 * g);
        float2 wv = *(const float2*)(wrow + e + 2 * g);
        bf16x8 xa = *(const bf16x8*)(XLc + (size_t)si.x * 768);
        bf16x8 xb = *(const bf16x8*)(XLc + (size_t)si.y * 768);
#pragma unroll
        for (int j = 0; j < 8; j++) acc[j] += wv.x * (float)xa[j] + wv.y * (float)xb[j];
    }
#pragma unroll
    for (int j = 0; j < 8; j++) {
        acc[j] += __shfl_xor(acc[j], 16);
        acc[j] += __shfl_xor(acc[j], 32);
    }
    if (lane < 16) {
        size_t o = (size_t)n * 768 + col;
        bf16x8 res;
#pragma unroll
        for (int j = 0; j < 8; j++) res[j] = (__bf16)acc[j];
        *(bf16x8*)(part + o) = res;
    }
}

// -------- head-mean over bf16 partials (head stride 128) + bias -> fp32 out --------
__global__ __launch_bounds__(128) void reduce_mean_k(const __bf16* __restrict__ part,
                                                     const float* __restrict__ b3,
                                                     float* __restrict__ out, int Nn) {
    int n = blockIdx.x;
    int t = threadIdx.x;
    if (t >= 121) return;
    const __bf16* row = part + (size_t)n * 768;
    float s = 0.f;
#pragma unroll
    for (int h = 0; h < 6; h++) s += (float)row[h * 128 + t];
    out[(size_t)n * 121 + t] = s * (1.f / 6.f) + b3[t];
}

// ---------------- LayerNorm + ELU ----------------
__global__ __launch_bounds__(256) void ln_elu_k(const __bf16* __restrict__ in,
                                                const float* __restrict__ g,
                                                const float* __restrict__ be,
                                                __bf16* __restrict__ out, int rows_real) {
    const int D = 1024;
    int n = blockIdx.x;
    int t = threadIdx.x;
    size_t ro = (size_t)n * D;
    if (n >= rows_real) {
#pragma unroll
        for (int j = 0; j < 4; j++) out[ro + t + 256 * j] = (__bf16)0.f;
        return;
    }
    float v[4];
    float s = 0.f, q = 0.f;
#pragma unroll
    for (int j = 0; j < 4; j++) {
        int c = t + 256 * j;
        float a = (float)in[ro + c];
        v[j] = a;
        s += a;
        q += a * a;
    }
#pragma unroll
    for (int off = 32; off; off >>= 1) {
        s += __shfl_down(s, off);
        q += __shfl_down(q, off);
    }
    __shared__ float rs[8];
    int wid = t >> 6;
    if ((t & 63) == 0) { rs[wid] = s; rs[wid + 4] = q; }
    __syncthreads();
    s = rs[0] + rs[1] + rs[2] + rs[3];
    q = rs[4] + rs[5] + rs[6] + rs[7];
    float mu = s * (1.f / 1024.f);
    float var = q * (1.f / 1024.f) - mu * mu;
    float inv = rsqrtf(fmaxf(var, 0.f) + 1e-5f);
#pragma unroll
    for (int j = 0; j < 4; j++) {
        int c = t + 256 * j;
        float y = (v[j] - mu) * inv * g[c] + be[c];
        y = y > 0.f ? y : expm1f(y);
        out[ro + c] = (__bf16)y;
    }
}

extern "C" void kernel_launch(void* const* d_in, const int* in_sizes, int n_in,
                              void* d_out, int out_size, void* d_ws, size_t ws_size,
                              hipStream_t stream) {
    const float* x   = (const float*)d_in[0];
    const int*   ei  = (const int*)d_in[1];
    const float* W1  = (const float*)d_in[2];
    const float* as1 = (const float*)d_in[3];
    const float* ad1 = (const float*)d_in[4];
    const float* b1  = (const float*)d_in[5];
    const float* W2  = (const float*)d_in[6];
    const float* as2 = (const float*)d_in[7];
    const float* ad2 = (const float*)d_in[8];
    const float* b2  = (const float*)d_in[9];
    const float* W3  = (const float*)d_in[10];
    const float* as3 = (const float*)d_in[11];
    const float* ad3 = (const float*)d_in[12];
    const float* b3  = (const float*)d_in[13];
    const float* sW1 = (const float*)d_in[14];
    const float* sb1 = (const float*)d_in[15];
    const float* sW2 = (const float*)d_in[16];
    const float* sb2 = (const float*)d_in[17];
    const float* g1  = (const float*)d_in[18];
    const float* be1 = (const float*)d_in[19];
    const float* g2  = (const float*)d_in[20];
    const float* be2 = (const float*)d_in[21];
    float* out = (float*)d_out;

    const int Nn = 20000;
    const int E = in_sizes[1] / 2;         // 320000
    const int E2 = E + Nn;                 // 340000
    const int Ecap = E2 + 8 * Nn;          // x8-padded CSR capacity (500000)
    const int Mpad = 20096;                // 157*128

    char* p = (char*)d_ws;
    auto alloc = [&](size_t bytes) {
        char* r = p;
        p += (bytes + 255) & ~(size_t)255;
        return r;
    };
    __bf16* WTcat1 = (__bf16*)alloc((size_t)2048 * 64 * 2);
    __bf16* WTcat2 = (__bf16*)alloc((size_t)2048 * 1024 * 2);
    __bf16* W3pT   = (__bf16*)alloc((size_t)768 * 1024 * 2);
    __bf16* xp     = (__bf16*)alloc((size_t)Mpad * 64 * 2);
    __bf16* XL     = (__bf16*)alloc((size_t)Mpad * 1024 * 2);
    __bf16* SK     = (__bf16*)alloc((size_t)Mpad * 1024 * 2);
    __bf16* H1     = (__bf16*)alloc((size_t)Mpad * 1024 * 2);
    float*  asrcb  = (float*)alloc((size_t)Nn * 6 * 4);
    float*  adstb  = (float*)alloc((size_t)Nn * 6 * 4);
    float*  wbuf   = (float*)alloc((size_t)6 * Ecap * 4);
    int*    rowp   = (int*)alloc((size_t)(Nn + 1) * 4);
    int*    cnt    = (int*)alloc((size_t)Nn * 4);
    int*    scsr   = (int*)alloc((size_t)Ecap * 4);
    int*    eiflag = (int*)alloc(256);
    __bf16* part   = SK;   // SK dead by layer 3
    (void)ws_size; (void)n_in; (void)out_size;

    // ---- prep (1 launch) ----
    prep_k<<<7968, 256, 0, stream>>>(x, W1, sW1, W2, sW2, W3, xp, WTcat1, WTcat2, W3pT, Nn);

    // ---- padded CSR ----
    zero_probe_k<<<(Nn + 255) / 256, 256, 0, stream>>>(ei, cnt, eiflag, Nn);
    hist_k<<<(E2 + 255) / 256, 256, 0, stream>>>(ei, eiflag, cnt, E, Nn);
    scan_k<<<1, 1024, 0, stream>>>(cnt, rowp, Nn);
    (void)hipMemsetAsync(scsr, 0, (size_t)Ecap * 4, stream);          // dummy src = 0
    (void)hipMemsetAsync(wbuf, 0, (size_t)6 * Ecap * 4, stream);      // dummy w = 0
    fill_csr_k<<<(E2 + 255) / 256, 256, 0, stream>>>(ei, eiflag, rowp, cnt, scsr, E, Nn);
    // cnt now holds real degrees

    // ---- layer 1: 50 -> 4x256 concat ----
    gemm_bt2<<<dim3(16, Mpad / 128), 256, 0, stream>>>(xp, WTcat1, XL, SK, Mpad, 64);
    alpha_k<<<(Nn * 4 * 64) / 256, 256, 0, stream>>>(XL, 1024, as1, ad1, asrcb, adstb, Nn, 4, 256, 256);
    attn_k<<<(Nn + 3) / 4, 256, 0, stream>>>(rowp, cnt, scsr, asrcb, adstb, wbuf, Nn, 4, Ecap);
    agg_skip8<<<dim3(8, (Nn + 3) / 4), 256, 0, stream>>>(XL, wbuf, rowp, scsr, b1, sb1, SK, Nn, Ecap);
    ln_elu_k<<<Mpad, 256, 0, stream>>>(SK, g1, be1, H1, Nn);

    // ---- layer 2: 1024 -> 4x256 concat ----
    gemm_bt2<<<dim3(16, Mpad / 128), 256, 0, stream>>>(H1, WTcat2, XL, SK, Mpad, 1024);
    alpha_k<<<(Nn * 4 * 64) / 256, 256, 0, stream>>>(XL, 1024, as2, ad2, asrcb, adstb, Nn, 4, 256, 256);
    attn_k<<<(Nn + 3) / 4, 256, 0, stream>>>(rowp, cnt, scsr, asrcb, adstb, wbuf, Nn, 4, Ecap);
    agg_skip8<<<dim3(8, (Nn + 3) / 4), 256, 0, stream>>>(XL, wbuf, rowp, scsr, b2, sb2, SK, Nn, Ecap);
    ln_elu_k<<<Mpad, 256, 0, stream>>>(SK, g2, be2, H1, Nn);  // H1 := h2

    // ---- layer 3: 1024 -> 6x(121 pad 128), mean over heads ----
    gemm_bt<<<dim3(6, Mpad / 128), 256, 0, stream>>>(H1, W3pT, XL, Mpad, 768, 1024);
    alpha_k<<<(Nn * 6 * 64) / 256, 256, 0, stream>>>(XL, 768, as3, ad3, asrcb, adstb, Nn, 6, 121, 128);
    attn_k<<<(Nn + 3) / 4, 256, 0, stream>>>(rowp, cnt, scsr, asrcb, adstb, wbuf, Nn, 6, Ecap);
    agg_mean8<<<dim3(6, (Nn + 3) / 4), 256, 0, stream>>>(XL, wbuf, rowp, scsr, part, Nn, Ecap);
    reduce_mean_k<<<Nn, 128, 0, stream>>>(part, b3, out, Nn);
}